// Round 11
// baseline (1954.366 us; speedup 1.0000x reference)
//
#include <hip/hip_runtime.h>

// CD_BP_Net R9 (2nd resubmit; bench never ran): two-phase gather.
//  - gatherF: pure permutation copy Fg[k]=F[inc[k]], 8-unrolled, low VGPR
//    -> ~256 random lines in flight per CU (2x R8's fused kernel).
//  - prodB: segmented product over SEQUENTIAL Fg (coalesced), boundary CAS.
//  - edge_fuse: 2 strided pairs/thread, batched independent loads.
//  - Fallback to R8 single-phase fused gather if ws_size < needed (+51MB Fg).

#define NBLK 256
#define QD 4
#define SENT 0x7fffffff

__device__ __forceinline__ float wave_red(float v) {
#pragma unroll
  for (int o = 32; o > 0; o >>= 1) v += __shfl_down(v, o, 64);
  return v;
}

__device__ __forceinline__ void atomicMulF(float* addr, float val) {
  unsigned int old = __float_as_uint(*addr), assumed;
  do {
    assumed = old;
    float nv = __uint_as_float(assumed) * val;
    old = atomicCAS((unsigned int*)addr, assumed, __float_as_uint(nv));
  } while (old != assumed);
}

// ---- CSR build ----------------------------------------------------------
__global__ void hist_rank(const int* __restrict__ ei, int* __restrict__ cnt,
                          int* __restrict__ rank, int E) {
  int G = gridDim.x * blockDim.x;
  int e[8], d[8];
#pragma unroll
  for (int j = 0; j < 8; ++j) {
    e[j] = blockIdx.x * blockDim.x + threadIdx.x + j * G;
    d[j] = (e[j] < E) ? ei[E + e[j]] : 0;
  }
#pragma unroll
  for (int j = 0; j < 8; ++j)
    if (e[j] < E) rank[e[j]] = atomicAdd(&cnt[d[j]], 1);
}

__global__ void scanA(const int* __restrict__ cnt, int* __restrict__ out,
                      int* __restrict__ bsum, int N) {
  __shared__ int lds[256];
  int base = blockIdx.x * 1024 + threadIdx.x * 4;
  int v0 = (base + 0 < N) ? cnt[base + 0] : 0;
  int v1 = (base + 1 < N) ? cnt[base + 1] : 0;
  int v2 = (base + 2 < N) ? cnt[base + 2] : 0;
  int v3 = (base + 3 < N) ? cnt[base + 3] : 0;
  lds[threadIdx.x] = v0 + v1 + v2 + v3;
  __syncthreads();
  for (int off = 1; off < 256; off <<= 1) {
    int x = (threadIdx.x >= off) ? lds[threadIdx.x - off] : 0;
    __syncthreads();
    if (threadIdx.x >= off) lds[threadIdx.x] += x;
    __syncthreads();
  }
  int excl = (threadIdx.x == 0) ? 0 : lds[threadIdx.x - 1];
  if (threadIdx.x == 255) bsum[blockIdx.x] = lds[255];
  if (base + 0 < N) out[base + 0] = excl;
  if (base + 1 < N) out[base + 1] = excl + v0;
  if (base + 2 < N) out[base + 2] = excl + v0 + v1;
  if (base + 3 < N) out[base + 3] = excl + v0 + v1 + v2;
}

__global__ void scanB(int* __restrict__ bsum, int NB) {
  __shared__ int lds[256];
  int v = (threadIdx.x < NB) ? bsum[threadIdx.x] : 0;
  lds[threadIdx.x] = v;
  __syncthreads();
  for (int off = 1; off < 256; off <<= 1) {
    int x = (threadIdx.x >= off) ? lds[threadIdx.x - off] : 0;
    __syncthreads();
    if (threadIdx.x >= off) lds[threadIdx.x] += x;
    __syncthreads();
  }
  int excl = (threadIdx.x == 0) ? 0 : lds[threadIdx.x - 1];
  if (threadIdx.x < NB) bsum[threadIdx.x] = excl;
}

__global__ void scanC(int* __restrict__ rowStart, const int* __restrict__ bsum,
                      int N, int E) {
  int i = blockIdx.x * blockDim.x + threadIdx.x;
  if (i < N) rowStart[i] += bsum[i >> 10];
  if (i == 0) rowStart[N] = E;
}

__global__ void scatter_inc(const int* __restrict__ ei, const int* __restrict__ rowStart,
                            const int* __restrict__ rank, int* __restrict__ inc, int E) {
  int G = gridDim.x * blockDim.x;
#pragma unroll
  for (int j = 0; j < 8; ++j) {
    int e = blockIdx.x * blockDim.x + threadIdx.x + j * G;
    if (e < E) {
      int d = ei[E + e];
      inc[rowStart[d] + rank[e]] = e;
    }
  }
}

__global__ void build_nodeOf(const int* __restrict__ rowStart, int* __restrict__ nodeOf,
                             int N) {
  int n = blockIdx.x * blockDim.x + threadIdx.x;
  if (n >= N) return;
  int s = rowStart[n], e = rowStart[n + 1];
  for (int k = s; k < e; ++k) nodeOf[k] = n;
}

// ---- setup: em, F0 = 1 + psi0*em, two_m (block-reduced) ----------------
__global__ void setup_pairs(const float* __restrict__ w, const float* __restrict__ msg,
                            const float* __restrict__ beta_p, float* __restrict__ F,
                            float* __restrict__ em_buf, double* __restrict__ two_m,
                            int Eh) {
  __shared__ float blk[4];
  int t = blockIdx.x * blockDim.x + threadIdx.x;
  float tw = 0.f;
  if (t < Eh) {
    float beta = beta_p[0];
    float wv = w[t];  // == w[t+Eh]
    tw = 2.f * wv;
    float em = expm1f(beta * wv);
    em_buf[t] = em;
    float4 m1 = *reinterpret_cast<const float4*>(&msg[(size_t)t * QD]);
    float4 m2 = *reinterpret_cast<const float4*>(&msg[((size_t)t + Eh) * QD]);
    float i1 = em / (m1.x + m1.y + m1.z + m1.w);
    float i2 = em / (m2.x + m2.y + m2.z + m2.w);
    float4 F1 = make_float4(fmaf(m1.x, i1, 1.f), fmaf(m1.y, i1, 1.f),
                            fmaf(m1.z, i1, 1.f), fmaf(m1.w, i1, 1.f));
    float4 F2 = make_float4(fmaf(m2.x, i2, 1.f), fmaf(m2.y, i2, 1.f),
                            fmaf(m2.z, i2, 1.f), fmaf(m2.w, i2, 1.f));
    *reinterpret_cast<float4*>(&F[(size_t)t * QD]) = F1;
    *reinterpret_cast<float4*>(&F[((size_t)t + Eh) * QD]) = F2;
  }
  tw = wave_red(tw);
  int wid = threadIdx.x >> 6;
  if ((threadIdx.x & 63) == 0) blk[wid] = tw;
  __syncthreads();
  if (threadIdx.x == 0)
    atomicAdd(two_m, (double)(blk[0] + blk[1] + blk[2] + blk[3]));
}

__global__ void fillP(float* __restrict__ P, int n4) {
  int i = blockIdx.x * blockDim.x + threadIdx.x;
  if (i < n4) P[i] = 1.0f;
}

// ---- phase A: pure permutation copy, max MLP ---------------------------
__global__ void gatherF(const int* __restrict__ inc, const float* __restrict__ F,
                        float* __restrict__ Fg, int E) {
  int G = gridDim.x * blockDim.x;
  int k[8], id[8];
#pragma unroll
  for (int j = 0; j < 8; ++j) {
    k[j] = blockIdx.x * blockDim.x + threadIdx.x + j * G;
    id[j] = (k[j] < E) ? inc[k[j]] : 0;
  }
  float4 v[8];
#pragma unroll
  for (int j = 0; j < 8; ++j)
    v[j] = *reinterpret_cast<const float4*>(&F[(size_t)id[j] * QD]);
#pragma unroll
  for (int j = 0; j < 8; ++j)
    if (k[j] < E) *reinterpret_cast<float4*>(&Fg[(size_t)k[j] * QD]) = v[j];
}

// ---- segmented combine: NW windows of 64 slots per wave -----------------
// SEQIDX: read src[k] sequentially (phase B); else src[inc[k]] (fused R8).
// PROD: multiply/identity-1/CAS-mult boundaries; else add/0/atomicAdd.
template <int NC, bool PROD, int NW, bool SEQIDX>
__global__ void gather_seg(const int* __restrict__ inc, const int* __restrict__ nodeOf,
                           const float* __restrict__ src, float* __restrict__ out,
                           int E) {
  const int lane = threadIdx.x & 63;
  const int wid = threadIdx.x >> 6;
  const long long base = ((long long)blockIdx.x * (blockDim.x >> 6) + wid) * (NW * 64);
  if (base >= E) return;
  const float IDENT = PROD ? 1.f : 0.f;
  int n[NW], idx[NW];
  float v[NW][NC];
#pragma unroll
  for (int w = 0; w < NW; ++w) {
    long long k = base + w * 64 + lane;
    n[w] = (k < E) ? nodeOf[k] : SENT;
    if constexpr (SEQIDX) idx[w] = (int)k;
    else idx[w] = (k < E) ? inc[k] : 0;
  }
#pragma unroll
  for (int w = 0; w < NW; ++w) {
    long long k = base + w * 64 + lane;
    if (k < E) {
      if constexpr (NC == 4) {
        float4 t = *reinterpret_cast<const float4*>(&src[(size_t)idx[w] * 4]);
        v[w][0] = t.x; v[w][1] = t.y; v[w][2] = t.z; v[w][3] = t.w;
      } else {
        v[w][0] = src[idx[w]];
      }
    } else {
#pragma unroll
      for (int c = 0; c < NC; ++c) v[w][c] = IDENT;
    }
  }
  int n00 = __shfl(n[0], 0, 64);
  int prevn = (base > 0) ? nodeOf[base - 1] : -1;
  const int incomplete = (prevn == n00) ? n00 : -1;
  int nwf[NW];
#pragma unroll
  for (int w = 0; w < NW - 1; ++w) nwf[w] = __shfl(n[w + 1], 0, 64);
  nwf[NW - 1] = (base + NW * 64 < E) ? nodeOf[base + NW * 64] : -1;

  float cv[NC];
#pragma unroll
  for (int c = 0; c < NC; ++c) cv[c] = IDENT;
  int cn = -1;
#pragma unroll
  for (int w = 0; w < NW; ++w) {
    int nn = n[w];
#pragma unroll
    for (int d = 1; d < 64; d <<= 1) {
      int pn = __shfl_up(nn, d, 64);
      float pv[NC];
#pragma unroll
      for (int c = 0; c < NC; ++c) pv[c] = __shfl_up(v[w][c], d, 64);
      if (lane >= d && pn == nn) {
#pragma unroll
        for (int c = 0; c < NC; ++c) {
          if constexpr (PROD) v[w][c] *= pv[c]; else v[w][c] += pv[c];
        }
      }
    }
    if (nn == cn) {
#pragma unroll
      for (int c = 0; c < NC; ++c) {
        if constexpr (PROD) v[w][c] *= cv[c]; else v[w][c] += cv[c];
      }
    }
    int nnext = __shfl_down(nn, 1, 64);
    if (lane == 63) nnext = nwf[w];
    bool segend = (nn != SENT) && (nnext != nn);
    if (segend) {
      if (nn == incomplete) {
#pragma unroll
        for (int c = 0; c < NC; ++c) {
          if constexpr (PROD) atomicMulF(&out[(size_t)nn * NC + c], v[w][c]);
          else atomicAdd(&out[(size_t)nn * NC + c], v[w][c]);
        }
      } else {
        if constexpr (NC == 4) {
          *reinterpret_cast<float4*>(&out[(size_t)nn * 4]) =
              make_float4(v[w][0], v[w][1], v[w][2], v[w][3]);
        } else {
          out[nn] = v[w][0];
        }
      }
    }
    int last_n = __shfl(nn, 63, 64);
    float lv[NC];
#pragma unroll
    for (int c = 0; c < NC; ++c) lv[c] = __shfl(v[w][c], 63, 64);
    bool last_end = (nwf[w] != last_n) || (last_n == SENT);
    if (last_end) {
      cn = -1;
#pragma unroll
      for (int c = 0; c < NC; ++c) cv[c] = IDENT;
    } else {
      cn = last_n;
#pragma unroll
      for (int c = 0; c < NC; ++c) cv[c] = lv[c];
    }
  }
  if (cn != -1 && lane == 0) {
#pragma unroll
    for (int c = 0; c < NC; ++c) {
      if constexpr (PROD) atomicMulF(&out[(size_t)cn * NC + c], cv[c]);
      else atomicAdd(&out[(size_t)cn * NC + c], cv[c]);
    }
  }
}

// ---- node: marg = eh*P/sum; hsum_new += deg*marg (block-reduced) -------
__global__ void node_post(const float* __restrict__ P, const float* __restrict__ deg,
                          const double* __restrict__ hsum_prev, double* __restrict__ hsum_new,
                          const float* __restrict__ beta_p, const double* __restrict__ two_m,
                          int N) {
  __shared__ float blk[4][4];
  int n = blockIdx.x * blockDim.x + threadIdx.x;
  float scale = -beta_p[0] / (float)two_m[0];
  float e0 = expf(scale * (float)hsum_prev[0]);
  float e1 = expf(scale * (float)hsum_prev[1]);
  float e2 = expf(scale * (float)hsum_prev[2]);
  float e3 = expf(scale * (float)hsum_prev[3]);
  float a0 = 0.f, a1 = 0.f, a2 = 0.f, a3 = 0.f;
  if (n < N) {
    float4 Pv = *reinterpret_cast<const float4*>(&P[(size_t)n * QD]);
    float m0 = e0 * Pv.x, m1 = e1 * Pv.y, m2 = e2 * Pv.z, m3 = e3 * Pv.w;
    float dinv = deg[n] / (m0 + m1 + m2 + m3);
    a0 = m0 * dinv; a1 = m1 * dinv; a2 = m2 * dinv; a3 = m3 * dinv;
  }
  a0 = wave_red(a0); a1 = wave_red(a1); a2 = wave_red(a2); a3 = wave_red(a3);
  int wid = threadIdx.x >> 6;
  if ((threadIdx.x & 63) == 0) {
    blk[wid][0] = a0; blk[wid][1] = a1; blk[wid][2] = a2; blk[wid][3] = a3;
  }
  __syncthreads();
  if (threadIdx.x < 4) {
    float s = blk[0][threadIdx.x] + blk[1][threadIdx.x] + blk[2][threadIdx.x] +
              blk[3][threadIdx.x];
    atomicAdd(&hsum_new[threadIdx.x], (double)s);
  }
}

__global__ void node_post_final(const float* __restrict__ P, const float* __restrict__ deg,
                                const double* __restrict__ hsum, const float* __restrict__ beta_p,
                                const double* __restrict__ two_m, float* __restrict__ out_s,
                                double* __restrict__ comm_raw, int N) {
  __shared__ float blk[4][4];
  int n = blockIdx.x * blockDim.x + threadIdx.x;
  float scale = -beta_p[0] / (float)two_m[0];
  float e0 = expf(scale * (float)hsum[0]);
  float e1 = expf(scale * (float)hsum[1]);
  float e2 = expf(scale * (float)hsum[2]);
  float e3 = expf(scale * (float)hsum[3]);
  float a0 = 0.f, a1 = 0.f, a2 = 0.f, a3 = 0.f;
  if (n < N) {
    float4 Pv = *reinterpret_cast<const float4*>(&P[(size_t)n * QD]);
    float m0 = e0 * Pv.x, m1 = e1 * Pv.y, m2 = e2 * Pv.z, m3 = e3 * Pv.w;
    float inv = 1.f / (m0 + m1 + m2 + m3);
    float4 s = make_float4(m0 * inv, m1 * inv, m2 * inv, m3 * inv);
    *reinterpret_cast<float4*>(&out_s[(size_t)n * QD]) = s;
    float d = deg[n];
    a0 = d * s.x; a1 = d * s.y; a2 = d * s.z; a3 = d * s.w;
  }
  a0 = wave_red(a0); a1 = wave_red(a1); a2 = wave_red(a2); a3 = wave_red(a3);
  int wid = threadIdx.x >> 6;
  if ((threadIdx.x & 63) == 0) {
    blk[wid][0] = a0; blk[wid][1] = a1; blk[wid][2] = a2; blk[wid][3] = a3;
  }
  __syncthreads();
  if (threadIdx.x < 4) {
    float s = blk[0][threadIdx.x] + blk[1][threadIdx.x] + blk[2][threadIdx.x] +
              blk[3][threadIdx.x];
    atomicAdd(&comm_raw[threadIdx.x], (double)s);
  }
}

// ---- cavity update, product form, 2 pairs/thread for MLP ---------------
__global__ void edge_fuse(const int* __restrict__ ei, const float* __restrict__ em_buf,
                          const float* __restrict__ P, float* __restrict__ F,
                          const double* __restrict__ hsum, const float* __restrict__ beta_p,
                          const double* __restrict__ two_m, int E, int Eh) {
  int G = gridDim.x * blockDim.x;
  int t0 = blockIdx.x * blockDim.x + threadIdx.x;
  int t1 = t0 + G;
  float scale = -beta_p[0] / (float)two_m[0];
  float e0 = expf(scale * (float)hsum[0]);
  float e1 = expf(scale * (float)hsum[1]);
  float e2 = expf(scale * (float)hsum[2]);
  float e3 = expf(scale * (float)hsum[3]);
  // batched independent loads for both pairs
  int s1a = 0, d1a = 0, s1b = 0, d1b = 0;
  float ema = 0.f, emb = 0.f;
  if (t0 < Eh) { s1a = ei[t0]; d1a = ei[E + t0]; ema = em_buf[t0]; }
  if (t1 < Eh) { s1b = ei[t1]; d1b = ei[E + t1]; emb = em_buf[t1]; }
  float4 F1a, F2a, F1b, F2b, Psa, Pda, Psb, Pdb;
  if (t0 < Eh) {
    F1a = *reinterpret_cast<const float4*>(&F[(size_t)t0 * QD]);
    F2a = *reinterpret_cast<const float4*>(&F[((size_t)t0 + Eh) * QD]);
    Psa = *reinterpret_cast<const float4*>(&P[(size_t)s1a * QD]);
    Pda = *reinterpret_cast<const float4*>(&P[(size_t)d1a * QD]);
  }
  if (t1 < Eh) {
    F1b = *reinterpret_cast<const float4*>(&F[(size_t)t1 * QD]);
    F2b = *reinterpret_cast<const float4*>(&F[((size_t)t1 + Eh) * QD]);
    Psb = *reinterpret_cast<const float4*>(&P[(size_t)s1b * QD]);
    Pdb = *reinterpret_cast<const float4*>(&P[(size_t)d1b * QD]);
  }
#define CAV(Fr, Pn, em, dstp)                                            \
  {                                                                      \
    float a01 = (Fr).x * (Fr).y, a23 = (Fr).z * (Fr).w;                  \
    float x0 = (Fr).y * a23, x1 = (Fr).x * a23;                          \
    float x2 = a01 * (Fr).w, x3 = a01 * (Fr).z;                          \
    float n0 = e0 * (Pn).x * x0, n1 = e1 * (Pn).y * x1;                  \
    float n2 = e2 * (Pn).z * x2, n3 = e3 * (Pn).w * x3;                  \
    float tt = (em) / (n0 + n1 + n2 + n3);                               \
    *reinterpret_cast<float4*>(dstp) =                                   \
        make_float4(fmaf(n0, tt, 1.f), fmaf(n1, tt, 1.f),                \
                    fmaf(n2, tt, 1.f), fmaf(n3, tt, 1.f));               \
  }
  if (t0 < Eh) {
    CAV(F2a, Psa, ema, &F[(size_t)t0 * QD]);
    CAV(F1a, Pda, ema, &F[((size_t)t0 + Eh) * QD]);
  }
  if (t1 < Eh) {
    CAV(F2b, Psb, emb, &F[(size_t)t1 * QD]);
    CAV(F1b, Pdb, emb, &F[((size_t)t1 + Eh) * QD]);
  }
#undef CAV
}

__global__ void edge_final(const int* __restrict__ ei, const float* __restrict__ w,
                           const float* __restrict__ out_s,
                           double* __restrict__ link_raw, int E, int Eh) {
  __shared__ float blk[4];
  int G = gridDim.x * blockDim.x;
  float c = 0.f;
  for (int t = blockIdx.x * blockDim.x + threadIdx.x; t < Eh; t += G) {
    int s1 = ei[t];
    int d1 = ei[E + t];
    float4 a = *reinterpret_cast<const float4*>(&out_s[(size_t)s1 * QD]);
    float4 b = *reinterpret_cast<const float4*>(&out_s[(size_t)d1 * QD]);
    float dot = a.x * b.x + a.y * b.y + a.z * b.z + a.w * b.w;
    c += 2.f * w[t] * dot;
  }
  c = wave_red(c);
  int wid = threadIdx.x >> 6;
  if ((threadIdx.x & 63) == 0) blk[wid] = c;
  __syncthreads();
  if (threadIdx.x == 0)
    atomicAdd(link_raw, (double)(blk[0] + blk[1] + blk[2] + blk[3]));
}

__global__ void finalize(const double* __restrict__ scal, float* __restrict__ out_q) {
  double tm = scal[0];
  double link = scal[1] / tm;
  double acc = 0.0;
#pragma unroll
  for (int k = 0; k < QD; ++k) {
    double c = scal[2 + k] / tm;
    acc += c * c;
  }
  out_q[0] = (float)(link - acc);
}

extern "C" void kernel_launch(void* const* d_in, const int* in_sizes, int n_in,
                              void* d_out, int out_size, void* d_ws, size_t ws_size,
                              hipStream_t stream) {
  const int* ei = (const int*)d_in[0];         // [2,E] int32
  const float* w = (const float*)d_in[1];      // [E]
  const float* msg = (const float*)d_in[2];    // [E,4]
  const float* beta_p = (const float*)d_in[3]; // scalar

  const int E = in_sizes[1];
  const int Eh = E / 2;
  const int N = (out_size - 1) / QD;

  // ws: scal [0]=two_m [1]=link [2..5]=comm [6+4i..]=hsum (i=0..10)
  char* p = (char*)d_ws;
  double* scal = (double*)p;
  size_t off = 512;
  int* cnt = (int*)(p + off); off += (size_t)N * 4;
  int* rowStart = (int*)(p + off); off += (size_t)(N + 1) * 4;
  off = (off + 127) & ~(size_t)127;
  int* bsum = (int*)(p + off); off += 1024;
  int* inc = (int*)(p + off); off += (size_t)E * 4;
  float* deg = (float*)(p + off); off += (size_t)N * 4;
  off = (off + 15) & ~(size_t)15;
  float* P = (float*)(p + off); off += (size_t)N * QD * 4;
  float* em = (float*)(p + off); off += (size_t)Eh * 4;
  off = (off + 15) & ~(size_t)15;
  float* F = (float*)(p + off); off += (size_t)E * QD * 4;
  int* rank = (int*)F;  // alias: rank dead before F is first written
  int* nodeOf = (int*)(p + off); off += (size_t)E * 4;
  off = (off + 15) & ~(size_t)15;
  float* Fg = (float*)(p + off); off += (size_t)E * QD * 4;  // phase-A scratch
  const bool twophase = ws_size >= off;  // host-side constant

  double* hs = scal + 6;
  const int gEdir = (E + NBLK - 1) / NBLK;
  const int gE = (Eh + NBLK - 1) / NBLK;
  const int gE2 = (Eh / 2 + NBLK - 1) / NBLK + 1;
  const int gN = (N + NBLK - 1) / NBLK;
  const int gH = (E + NBLK * 8 - 1) / (NBLK * 8);
  const int gGF = (E + NBLK * 8 - 1) / (NBLK * 8);
  const int gWp = (E + 2047) / 2048;   // fused PROD (fallback)
  const int gWd = (E + 1023) / 1024;   // deg SUM
  const int gF = (4 * N + NBLK - 1) / NBLK;
  const int NBscan = (N + 1023) / 1024;

  hipMemsetAsync(scal, 0, 512, stream);
  hipMemsetAsync(cnt, 0, (size_t)N * 4, stream);
  hipMemsetAsync(deg, 0, (size_t)N * 4, stream);

  hist_rank<<<gH, NBLK, 0, stream>>>(ei, cnt, rank, E);
  scanA<<<NBscan, 256, 0, stream>>>(cnt, rowStart, bsum, N);
  scanB<<<1, 256, 0, stream>>>(bsum, NBscan);
  scanC<<<(N + NBLK) / NBLK, NBLK, 0, stream>>>(rowStart, bsum, N, E);
  scatter_inc<<<gH, NBLK, 0, stream>>>(ei, rowStart, rank, inc, E);
  build_nodeOf<<<gN, NBLK, 0, stream>>>(rowStart, nodeOf, N);

  setup_pairs<<<gE, NBLK, 0, stream>>>(w, msg, beta_p, F, em, scal, Eh);
  gather_seg<1, false, 4, false><<<gWd, NBLK, 0, stream>>>(inc, nodeOf, w, deg, E);

  float* out_s = (float*)d_out;
  for (int i = 1; i <= 11; ++i) {
    fillP<<<gF, NBLK, 0, stream>>>(P, 4 * N);
    if (twophase) {
      gatherF<<<gGF, NBLK, 0, stream>>>(inc, F, Fg, E);
      gather_seg<4, true, 8, true><<<gWp, NBLK, 0, stream>>>(inc, nodeOf, Fg, P, E);
    } else {
      gather_seg<4, true, 8, false><<<gWp, NBLK, 0, stream>>>(inc, nodeOf, F, P, E);
    }
    if (i <= 10) {
      node_post<<<gN, NBLK, 0, stream>>>(P, deg, hs + 4 * (i - 1), hs + 4 * i,
                                         beta_p, scal, N);
      edge_fuse<<<gE2, NBLK, 0, stream>>>(ei, em, P, F, hs + 4 * i, beta_p, scal, E, Eh);
    }
  }
  node_post_final<<<gN, NBLK, 0, stream>>>(P, deg, hs + 40, beta_p, scal,
                                           out_s, scal + 2, N);
  edge_final<<<512, NBLK, 0, stream>>>(ei, w, out_s, scal + 1, E, Eh);
  finalize<<<1, 1, 0, stream>>>(scal, out_s + (size_t)N * QD);
}

// Round 12
// 1948.380 us; speedup vs baseline: 1.0031x; 1.0031x over previous
//
#include <hip/hip_runtime.h>

// CD_BP_Net R12: CSR-resident edge state (pay the permutation ONCE/iter).
//  F stored in dst-CSR order, double-buffered (F_A/F_B):
//   - pass1: segmented PRODUCT over SEQUENTIAL F_csr -> P. No random reads.
//   - cavity_csr: F_new[k] = g(P[srcOf[k]], F_old[revslot[k]], em_csr[k]).
//     One random 16B read per slot (the single permutation) + seq write.
//  One-time: csrPos scatter, build_csrmeta (srcOf/em_csr/revslot/F0_csr).
//  Fallback to R8 fused path (proven 1719us) if ws_size < ~163MB.

#define NBLK 256
#define QD 4
#define SENT 0x7fffffff

__device__ __forceinline__ float wave_red(float v) {
#pragma unroll
  for (int o = 32; o > 0; o >>= 1) v += __shfl_down(v, o, 64);
  return v;
}

__device__ __forceinline__ void atomicMulF(float* addr, float val) {
  unsigned int old = __float_as_uint(*addr), assumed;
  do {
    assumed = old;
    float nv = __uint_as_float(assumed) * val;
    old = atomicCAS((unsigned int*)addr, assumed, __float_as_uint(nv));
  } while (old != assumed);
}

// ---- CSR build ----------------------------------------------------------
__global__ void hist_rank(const int* __restrict__ ei, int* __restrict__ cnt,
                          int* __restrict__ rank, int E) {
  int G = gridDim.x * blockDim.x;
  int e[8], d[8];
#pragma unroll
  for (int j = 0; j < 8; ++j) {
    e[j] = blockIdx.x * blockDim.x + threadIdx.x + j * G;
    d[j] = (e[j] < E) ? ei[E + e[j]] : 0;
  }
#pragma unroll
  for (int j = 0; j < 8; ++j)
    if (e[j] < E) rank[e[j]] = atomicAdd(&cnt[d[j]], 1);
}

__global__ void scanA(const int* __restrict__ cnt, int* __restrict__ out,
                      int* __restrict__ bsum, int N) {
  __shared__ int lds[256];
  int base = blockIdx.x * 1024 + threadIdx.x * 4;
  int v0 = (base + 0 < N) ? cnt[base + 0] : 0;
  int v1 = (base + 1 < N) ? cnt[base + 1] : 0;
  int v2 = (base + 2 < N) ? cnt[base + 2] : 0;
  int v3 = (base + 3 < N) ? cnt[base + 3] : 0;
  lds[threadIdx.x] = v0 + v1 + v2 + v3;
  __syncthreads();
  for (int off = 1; off < 256; off <<= 1) {
    int x = (threadIdx.x >= off) ? lds[threadIdx.x - off] : 0;
    __syncthreads();
    if (threadIdx.x >= off) lds[threadIdx.x] += x;
    __syncthreads();
  }
  int excl = (threadIdx.x == 0) ? 0 : lds[threadIdx.x - 1];
  if (threadIdx.x == 255) bsum[blockIdx.x] = lds[255];
  if (base + 0 < N) out[base + 0] = excl;
  if (base + 1 < N) out[base + 1] = excl + v0;
  if (base + 2 < N) out[base + 2] = excl + v0 + v1;
  if (base + 3 < N) out[base + 3] = excl + v0 + v1 + v2;
}

__global__ void scanB(int* __restrict__ bsum, int NB) {
  __shared__ int lds[256];
  int v = (threadIdx.x < NB) ? bsum[threadIdx.x] : 0;
  lds[threadIdx.x] = v;
  __syncthreads();
  for (int off = 1; off < 256; off <<= 1) {
    int x = (threadIdx.x >= off) ? lds[threadIdx.x - off] : 0;
    __syncthreads();
    if (threadIdx.x >= off) lds[threadIdx.x] += x;
    __syncthreads();
  }
  int excl = (threadIdx.x == 0) ? 0 : lds[threadIdx.x - 1];
  if (threadIdx.x < NB) bsum[threadIdx.x] = excl;
}

__global__ void scanC(int* __restrict__ rowStart, const int* __restrict__ bsum,
                      int N, int E) {
  int i = blockIdx.x * blockDim.x + threadIdx.x;
  if (i < N) rowStart[i] += bsum[i >> 10];
  if (i == 0) rowStart[N] = E;
}

// scatter inc AND csrPos (inverse permutation)
__global__ void scatter_inc2(const int* __restrict__ ei, const int* __restrict__ rowStart,
                             const int* __restrict__ rank, int* __restrict__ inc,
                             int* __restrict__ csrPos, int E) {
  int G = gridDim.x * blockDim.x;
#pragma unroll
  for (int j = 0; j < 4; ++j) {
    int e = blockIdx.x * blockDim.x + threadIdx.x + j * G;
    if (e < E) {
      int d = ei[E + e];
      int pos = rowStart[d] + rank[e];
      inc[pos] = e;
      csrPos[e] = pos;
    }
  }
}

__global__ void build_nodeOf(const int* __restrict__ rowStart, int* __restrict__ nodeOf,
                             int N) {
  int n = blockIdx.x * blockDim.x + threadIdx.x;
  if (n >= N) return;
  int s = rowStart[n], e = rowStart[n + 1];
  for (int k = s; k < e; ++k) nodeOf[k] = n;
}

// ---- setup: em, (optional F0 edge-order), two_m ------------------------
__global__ void setup_pairs(const float* __restrict__ w, const float* __restrict__ msg,
                            const float* __restrict__ beta_p, float* __restrict__ F,
                            float* __restrict__ em_buf, double* __restrict__ two_m,
                            int Eh, int writeF) {
  __shared__ float blk[4];
  int t = blockIdx.x * blockDim.x + threadIdx.x;
  float tw = 0.f;
  if (t < Eh) {
    float beta = beta_p[0];
    float wv = w[t];  // == w[t+Eh]
    tw = 2.f * wv;
    float em = expm1f(beta * wv);
    em_buf[t] = em;
    if (writeF) {
      float4 m1 = *reinterpret_cast<const float4*>(&msg[(size_t)t * QD]);
      float4 m2 = *reinterpret_cast<const float4*>(&msg[((size_t)t + Eh) * QD]);
      float i1 = em / (m1.x + m1.y + m1.z + m1.w);
      float i2 = em / (m2.x + m2.y + m2.z + m2.w);
      float4 F1 = make_float4(fmaf(m1.x, i1, 1.f), fmaf(m1.y, i1, 1.f),
                              fmaf(m1.z, i1, 1.f), fmaf(m1.w, i1, 1.f));
      float4 F2 = make_float4(fmaf(m2.x, i2, 1.f), fmaf(m2.y, i2, 1.f),
                              fmaf(m2.z, i2, 1.f), fmaf(m2.w, i2, 1.f));
      *reinterpret_cast<float4*>(&F[(size_t)t * QD]) = F1;
      *reinterpret_cast<float4*>(&F[((size_t)t + Eh) * QD]) = F2;
    }
  }
  tw = wave_red(tw);
  int wid = threadIdx.x >> 6;
  if ((threadIdx.x & 63) == 0) blk[wid] = tw;
  __syncthreads();
  if (threadIdx.x == 0)
    atomicAdd(two_m, (double)(blk[0] + blk[1] + blk[2] + blk[3]));
}

// one-time CSR metadata + F0 in CSR order
__global__ void build_csrmeta(const int* __restrict__ inc, const int* __restrict__ csrPos,
                              const int* __restrict__ ei, const float* __restrict__ em,
                              const float* __restrict__ msg, int* __restrict__ srcOf,
                              float* __restrict__ em_csr, int* __restrict__ revslot,
                              float* __restrict__ F0csr, int E, int Eh) {
  int G = gridDim.x * blockDim.x;
#pragma unroll
  for (int j = 0; j < 4; ++j) {
    int k = blockIdx.x * blockDim.x + threadIdx.x + j * G;
    if (k >= E) continue;
    int e = inc[k];
    int pr = (e < Eh) ? e : e - Eh;
    int re = (e < Eh) ? e + Eh : e - Eh;
    float emv = em[pr];
    srcOf[k] = ei[e];
    em_csr[k] = emv;
    revslot[k] = csrPos[re];
    float4 m = *reinterpret_cast<const float4*>(&msg[(size_t)e * QD]);
    float i1 = emv / (m.x + m.y + m.z + m.w);
    *reinterpret_cast<float4*>(&F0csr[(size_t)k * QD]) =
        make_float4(fmaf(m.x, i1, 1.f), fmaf(m.y, i1, 1.f),
                    fmaf(m.z, i1, 1.f), fmaf(m.w, i1, 1.f));
  }
}

__global__ void fillP(float* __restrict__ P, int n4) {
  int i = blockIdx.x * blockDim.x + threadIdx.x;
  if (i < n4) P[i] = 1.0f;
}

// ---- segmented combine (pass1 / deg / fallback gather) ------------------
template <int NC, bool PROD, int NW, bool SEQIDX>
__global__ void gather_seg(const int* __restrict__ inc, const int* __restrict__ nodeOf,
                           const float* __restrict__ src, float* __restrict__ out,
                           int E) {
  const int lane = threadIdx.x & 63;
  const int wid = threadIdx.x >> 6;
  const long long base = ((long long)blockIdx.x * (blockDim.x >> 6) + wid) * (NW * 64);
  if (base >= E) return;
  const float IDENT = PROD ? 1.f : 0.f;
  int n[NW], idx[NW];
  float v[NW][NC];
#pragma unroll
  for (int w = 0; w < NW; ++w) {
    long long k = base + w * 64 + lane;
    n[w] = (k < E) ? nodeOf[k] : SENT;
    if constexpr (SEQIDX) idx[w] = (int)k;
    else idx[w] = (k < E) ? inc[k] : 0;
  }
#pragma unroll
  for (int w = 0; w < NW; ++w) {
    long long k = base + w * 64 + lane;
    if (k < E) {
      if constexpr (NC == 4) {
        float4 t = *reinterpret_cast<const float4*>(&src[(size_t)idx[w] * 4]);
        v[w][0] = t.x; v[w][1] = t.y; v[w][2] = t.z; v[w][3] = t.w;
      } else {
        v[w][0] = src[idx[w]];
      }
    } else {
#pragma unroll
      for (int c = 0; c < NC; ++c) v[w][c] = IDENT;
    }
  }
  int n00 = __shfl(n[0], 0, 64);
  int prevn = (base > 0) ? nodeOf[base - 1] : -1;
  const int incomplete = (prevn == n00) ? n00 : -1;
  int nwf[NW];
#pragma unroll
  for (int w = 0; w < NW - 1; ++w) nwf[w] = __shfl(n[w + 1], 0, 64);
  nwf[NW - 1] = (base + NW * 64 < E) ? nodeOf[base + NW * 64] : -1;

  float cv[NC];
#pragma unroll
  for (int c = 0; c < NC; ++c) cv[c] = IDENT;
  int cn = -1;
#pragma unroll
  for (int w = 0; w < NW; ++w) {
    int nn = n[w];
#pragma unroll
    for (int d = 1; d < 64; d <<= 1) {
      int pn = __shfl_up(nn, d, 64);
      float pv[NC];
#pragma unroll
      for (int c = 0; c < NC; ++c) pv[c] = __shfl_up(v[w][c], d, 64);
      if (lane >= d && pn == nn) {
#pragma unroll
        for (int c = 0; c < NC; ++c) {
          if constexpr (PROD) v[w][c] *= pv[c]; else v[w][c] += pv[c];
        }
      }
    }
    if (nn == cn) {
#pragma unroll
      for (int c = 0; c < NC; ++c) {
        if constexpr (PROD) v[w][c] *= cv[c]; else v[w][c] += cv[c];
      }
    }
    int nnext = __shfl_down(nn, 1, 64);
    if (lane == 63) nnext = nwf[w];
    bool segend = (nn != SENT) && (nnext != nn);
    if (segend) {
      if (nn == incomplete) {
#pragma unroll
        for (int c = 0; c < NC; ++c) {
          if constexpr (PROD) atomicMulF(&out[(size_t)nn * NC + c], v[w][c]);
          else atomicAdd(&out[(size_t)nn * NC + c], v[w][c]);
        }
      } else {
        if constexpr (NC == 4) {
          *reinterpret_cast<float4*>(&out[(size_t)nn * 4]) =
              make_float4(v[w][0], v[w][1], v[w][2], v[w][3]);
        } else {
          out[nn] = v[w][0];
        }
      }
    }
    int last_n = __shfl(nn, 63, 64);
    float lv[NC];
#pragma unroll
    for (int c = 0; c < NC; ++c) lv[c] = __shfl(v[w][c], 63, 64);
    bool last_end = (nwf[w] != last_n) || (last_n == SENT);
    if (last_end) {
      cn = -1;
#pragma unroll
      for (int c = 0; c < NC; ++c) cv[c] = IDENT;
    } else {
      cn = last_n;
#pragma unroll
      for (int c = 0; c < NC; ++c) cv[c] = lv[c];
    }
  }
  if (cn != -1 && lane == 0) {
#pragma unroll
    for (int c = 0; c < NC; ++c) {
      if constexpr (PROD) atomicMulF(&out[(size_t)cn * NC + c], cv[c]);
      else atomicAdd(&out[(size_t)cn * NC + c], cv[c]);
    }
  }
}

// ---- cavity in CSR space: one random read per slot ---------------------
__global__ void cavity_csr(const int* __restrict__ srcOf, const int* __restrict__ revslot,
                           const float* __restrict__ em_csr, const float* __restrict__ P,
                           const float* __restrict__ F_old, float* __restrict__ F_new,
                           const double* __restrict__ hsum, const float* __restrict__ beta_p,
                           const double* __restrict__ two_m, int E) {
  int G = gridDim.x * blockDim.x;
  float scale = -beta_p[0] / (float)two_m[0];
  float e0 = expf(scale * (float)hsum[0]);
  float e1 = expf(scale * (float)hsum[1]);
  float e2 = expf(scale * (float)hsum[2]);
  float e3 = expf(scale * (float)hsum[3]);
  int k[4], rs[4], sc[4];
  float emv[4];
#pragma unroll
  for (int j = 0; j < 4; ++j) {
    k[j] = blockIdx.x * blockDim.x + threadIdx.x + j * G;
    bool ok = k[j] < E;
    rs[j] = ok ? revslot[k[j]] : 0;
    sc[j] = ok ? srcOf[k[j]] : 0;
    emv[j] = ok ? em_csr[k[j]] : 0.f;
  }
  float4 Fr[4], Ps[4];
#pragma unroll
  for (int j = 0; j < 4; ++j) {
    Fr[j] = *reinterpret_cast<const float4*>(&F_old[(size_t)rs[j] * QD]);
    Ps[j] = *reinterpret_cast<const float4*>(&P[(size_t)sc[j] * QD]);
  }
#pragma unroll
  for (int j = 0; j < 4; ++j) {
    if (k[j] >= E) continue;
    float a01 = Fr[j].x * Fr[j].y, a23 = Fr[j].z * Fr[j].w;
    float x0 = Fr[j].y * a23, x1 = Fr[j].x * a23;
    float x2 = a01 * Fr[j].w, x3 = a01 * Fr[j].z;
    float n0 = e0 * Ps[j].x * x0, n1 = e1 * Ps[j].y * x1;
    float n2 = e2 * Ps[j].z * x2, n3 = e3 * Ps[j].w * x3;
    float tt = emv[j] / (n0 + n1 + n2 + n3);
    *reinterpret_cast<float4*>(&F_new[(size_t)k[j] * QD]) =
        make_float4(fmaf(n0, tt, 1.f), fmaf(n1, tt, 1.f),
                    fmaf(n2, tt, 1.f), fmaf(n3, tt, 1.f));
  }
}

// ---- fallback (R8) cavity: edge-order paired, in-place -----------------
__global__ void edge_fuse(const int* __restrict__ ei, const float* __restrict__ em_buf,
                          const float* __restrict__ P, float* __restrict__ F,
                          const double* __restrict__ hsum, const float* __restrict__ beta_p,
                          const double* __restrict__ two_m, int E, int Eh) {
  int t = blockIdx.x * blockDim.x + threadIdx.x;
  if (t >= Eh) return;
  float scale = -beta_p[0] / (float)two_m[0];
  float e0 = expf(scale * (float)hsum[0]);
  float e1 = expf(scale * (float)hsum[1]);
  float e2 = expf(scale * (float)hsum[2]);
  float e3 = expf(scale * (float)hsum[3]);
  int s1 = ei[t];
  int d1 = ei[E + t];
  float em = em_buf[t];
  float4 F1 = *reinterpret_cast<const float4*>(&F[(size_t)t * QD]);
  float4 F2 = *reinterpret_cast<const float4*>(&F[((size_t)t + Eh) * QD]);
  float4 Ps = *reinterpret_cast<const float4*>(&P[(size_t)s1 * QD]);
  float4 Pd = *reinterpret_cast<const float4*>(&P[(size_t)d1 * QD]);
  {
    float a01 = F2.x * F2.y, a23 = F2.z * F2.w;
    float x0 = F2.y * a23, x1 = F2.x * a23, x2 = a01 * F2.w, x3 = a01 * F2.z;
    float n0 = e0 * Ps.x * x0, n1 = e1 * Ps.y * x1;
    float n2 = e2 * Ps.z * x2, n3 = e3 * Ps.w * x3;
    float tt = em / (n0 + n1 + n2 + n3);
    *reinterpret_cast<float4*>(&F[(size_t)t * QD]) =
        make_float4(fmaf(n0, tt, 1.f), fmaf(n1, tt, 1.f),
                    fmaf(n2, tt, 1.f), fmaf(n3, tt, 1.f));
  }
  {
    float a01 = F1.x * F1.y, a23 = F1.z * F1.w;
    float x0 = F1.y * a23, x1 = F1.x * a23, x2 = a01 * F1.w, x3 = a01 * F1.z;
    float n0 = e0 * Pd.x * x0, n1 = e1 * Pd.y * x1;
    float n2 = e2 * Pd.z * x2, n3 = e3 * Pd.w * x3;
    float tt = em / (n0 + n1 + n2 + n3);
    *reinterpret_cast<float4*>(&F[((size_t)t + Eh) * QD]) =
        make_float4(fmaf(n0, tt, 1.f), fmaf(n1, tt, 1.f),
                    fmaf(n2, tt, 1.f), fmaf(n3, tt, 1.f));
  }
}

// ---- node kernels ------------------------------------------------------
__global__ void node_post(const float* __restrict__ P, const float* __restrict__ deg,
                          const double* __restrict__ hsum_prev, double* __restrict__ hsum_new,
                          const float* __restrict__ beta_p, const double* __restrict__ two_m,
                          int N) {
  __shared__ float blk[4][4];
  int n = blockIdx.x * blockDim.x + threadIdx.x;
  float scale = -beta_p[0] / (float)two_m[0];
  float e0 = expf(scale * (float)hsum_prev[0]);
  float e1 = expf(scale * (float)hsum_prev[1]);
  float e2 = expf(scale * (float)hsum_prev[2]);
  float e3 = expf(scale * (float)hsum_prev[3]);
  float a0 = 0.f, a1 = 0.f, a2 = 0.f, a3 = 0.f;
  if (n < N) {
    float4 Pv = *reinterpret_cast<const float4*>(&P[(size_t)n * QD]);
    float m0 = e0 * Pv.x, m1 = e1 * Pv.y, m2 = e2 * Pv.z, m3 = e3 * Pv.w;
    float dinv = deg[n] / (m0 + m1 + m2 + m3);
    a0 = m0 * dinv; a1 = m1 * dinv; a2 = m2 * dinv; a3 = m3 * dinv;
  }
  a0 = wave_red(a0); a1 = wave_red(a1); a2 = wave_red(a2); a3 = wave_red(a3);
  int wid = threadIdx.x >> 6;
  if ((threadIdx.x & 63) == 0) {
    blk[wid][0] = a0; blk[wid][1] = a1; blk[wid][2] = a2; blk[wid][3] = a3;
  }
  __syncthreads();
  if (threadIdx.x < 4) {
    float s = blk[0][threadIdx.x] + blk[1][threadIdx.x] + blk[2][threadIdx.x] +
              blk[3][threadIdx.x];
    atomicAdd(&hsum_new[threadIdx.x], (double)s);
  }
}

__global__ void node_post_final(const float* __restrict__ P, const float* __restrict__ deg,
                                const double* __restrict__ hsum, const float* __restrict__ beta_p,
                                const double* __restrict__ two_m, float* __restrict__ out_s,
                                double* __restrict__ comm_raw, int N) {
  __shared__ float blk[4][4];
  int n = blockIdx.x * blockDim.x + threadIdx.x;
  float scale = -beta_p[0] / (float)two_m[0];
  float e0 = expf(scale * (float)hsum[0]);
  float e1 = expf(scale * (float)hsum[1]);
  float e2 = expf(scale * (float)hsum[2]);
  float e3 = expf(scale * (float)hsum[3]);
  float a0 = 0.f, a1 = 0.f, a2 = 0.f, a3 = 0.f;
  if (n < N) {
    float4 Pv = *reinterpret_cast<const float4*>(&P[(size_t)n * QD]);
    float m0 = e0 * Pv.x, m1 = e1 * Pv.y, m2 = e2 * Pv.z, m3 = e3 * Pv.w;
    float inv = 1.f / (m0 + m1 + m2 + m3);
    float4 s = make_float4(m0 * inv, m1 * inv, m2 * inv, m3 * inv);
    *reinterpret_cast<float4*>(&out_s[(size_t)n * QD]) = s;
    float d = deg[n];
    a0 = d * s.x; a1 = d * s.y; a2 = d * s.z; a3 = d * s.w;
  }
  a0 = wave_red(a0); a1 = wave_red(a1); a2 = wave_red(a2); a3 = wave_red(a3);
  int wid = threadIdx.x >> 6;
  if ((threadIdx.x & 63) == 0) {
    blk[wid][0] = a0; blk[wid][1] = a1; blk[wid][2] = a2; blk[wid][3] = a3;
  }
  __syncthreads();
  if (threadIdx.x < 4) {
    float s = blk[0][threadIdx.x] + blk[1][threadIdx.x] + blk[2][threadIdx.x] +
              blk[3][threadIdx.x];
    atomicAdd(&comm_raw[threadIdx.x], (double)s);
  }
}

__global__ void edge_final(const int* __restrict__ ei, const float* __restrict__ w,
                           const float* __restrict__ out_s,
                           double* __restrict__ link_raw, int E, int Eh) {
  __shared__ float blk[4];
  int G = gridDim.x * blockDim.x;
  float c = 0.f;
  for (int t = blockIdx.x * blockDim.x + threadIdx.x; t < Eh; t += G) {
    int s1 = ei[t];
    int d1 = ei[E + t];
    float4 a = *reinterpret_cast<const float4*>(&out_s[(size_t)s1 * QD]);
    float4 b = *reinterpret_cast<const float4*>(&out_s[(size_t)d1 * QD]);
    float dot = a.x * b.x + a.y * b.y + a.z * b.z + a.w * b.w;
    c += 2.f * w[t] * dot;
  }
  c = wave_red(c);
  int wid = threadIdx.x >> 6;
  if ((threadIdx.x & 63) == 0) blk[wid] = c;
  __syncthreads();
  if (threadIdx.x == 0)
    atomicAdd(link_raw, (double)(blk[0] + blk[1] + blk[2] + blk[3]));
}

__global__ void finalize(const double* __restrict__ scal, float* __restrict__ out_q) {
  double tm = scal[0];
  double link = scal[1] / tm;
  double acc = 0.0;
#pragma unroll
  for (int k = 0; k < QD; ++k) {
    double c = scal[2 + k] / tm;
    acc += c * c;
  }
  out_q[0] = (float)(link - acc);
}

extern "C" void kernel_launch(void* const* d_in, const int* in_sizes, int n_in,
                              void* d_out, int out_size, void* d_ws, size_t ws_size,
                              hipStream_t stream) {
  const int* ei = (const int*)d_in[0];         // [2,E] int32
  const float* w = (const float*)d_in[1];      // [E]
  const float* msg = (const float*)d_in[2];    // [E,4]
  const float* beta_p = (const float*)d_in[3]; // scalar

  const int E = in_sizes[1];
  const int Eh = E / 2;
  const int N = (out_size - 1) / QD;

  // ws layout (v2 = CSR-resident double-buffer):
  char* p = (char*)d_ws;
  double* scal = (double*)p;
  size_t off = 512;
  int* cnt = (int*)(p + off); off += (size_t)N * 4;
  int* rowStart = (int*)(p + off); off += (size_t)(N + 1) * 4;
  off = (off + 127) & ~(size_t)127;
  int* bsum = (int*)(p + off); off += 1024;
  float* deg = (float*)(p + off); off += (size_t)N * 4;
  off = (off + 15) & ~(size_t)15;
  float* P = (float*)(p + off); off += (size_t)N * QD * 4;
  float* em = (float*)(p + off); off += (size_t)Eh * 4;
  int* nodeOf = (int*)(p + off); off += (size_t)E * 4;
  int* srcOf = (int*)(p + off); off += (size_t)E * 4;
  float* em_csr = (float*)(p + off); off += (size_t)E * 4;
  int* revslot = (int*)(p + off); off += (size_t)E * 4;
  off = (off + 15) & ~(size_t)15;
  float* F_A = (float*)(p + off); off += (size_t)E * QD * 4;
  size_t offB = off;
  float* F_B = (float*)(p + off); off += (size_t)E * QD * 4;
  // aliases (setup lifetimes only):
  int* rank = (int*)F_A;              // dead after scatter_inc2; F_A written later
  int* csrPos = (int*)F_B;            // dead after build_csrmeta; F_B written iter1
  int* inc = (int*)F_B + E;           // v2: dead after setup. fallback: persistent
  const size_t need_fallback = offB + (size_t)2 * E * 4;  // F_B prefix holds csrPos+inc
  const bool v2 = ws_size >= off;     // host-side constant
  // (fallback requires ws_size >= need_fallback; proven by R11's twophase run)
  (void)need_fallback;

  double* hs = scal + 6;  // hsum[iter i] at hs + 4*i
  const int gE = (Eh + NBLK - 1) / NBLK;
  const int gN = (N + NBLK - 1) / NBLK;
  const int gH = (E + NBLK * 8 - 1) / (NBLK * 8);
  const int gS4 = (E + NBLK * 4 - 1) / (NBLK * 4);
  const int gWs = (E + 1023) / 1024;   // gather_seg NW=4
  const int gWp = (E + 2047) / 2048;   // fallback fused PROD NW=8
  const int gF = (4 * N + NBLK - 1) / NBLK;
  const int NBscan = (N + 1023) / 1024;

  hipMemsetAsync(scal, 0, 512, stream);
  hipMemsetAsync(cnt, 0, (size_t)N * 4, stream);
  hipMemsetAsync(deg, 0, (size_t)N * 4, stream);

  hist_rank<<<gH, NBLK, 0, stream>>>(ei, cnt, rank, E);
  scanA<<<NBscan, 256, 0, stream>>>(cnt, rowStart, bsum, N);
  scanB<<<1, 256, 0, stream>>>(bsum, NBscan);
  scanC<<<(N + NBLK) / NBLK, NBLK, 0, stream>>>(rowStart, bsum, N, E);
  scatter_inc2<<<gS4, NBLK, 0, stream>>>(ei, rowStart, rank, inc, csrPos, E);
  build_nodeOf<<<gN, NBLK, 0, stream>>>(rowStart, nodeOf, N);

  setup_pairs<<<gE, NBLK, 0, stream>>>(w, msg, beta_p, F_A, em, scal, Eh, v2 ? 0 : 1);
  if (v2)
    build_csrmeta<<<gS4, NBLK, 0, stream>>>(inc, csrPos, ei, em, msg, srcOf,
                                            em_csr, revslot, F_A, E, Eh);
  gather_seg<1, false, 4, false><<<gWs, NBLK, 0, stream>>>(inc, nodeOf, w, deg, E);

  float* out_s = (float*)d_out;
  float* Fc = F_A;  // current
  float* Fn = F_B;  // next
  for (int i = 1; i <= 11; ++i) {
    fillP<<<gF, NBLK, 0, stream>>>(P, 4 * N);
    if (v2)
      gather_seg<4, true, 4, true><<<gWs, NBLK, 0, stream>>>(inc, nodeOf, Fc, P, E);
    else
      gather_seg<4, true, 8, false><<<gWp, NBLK, 0, stream>>>(inc, nodeOf, F_A, P, E);
    if (i <= 10) {
      node_post<<<gN, NBLK, 0, stream>>>(P, deg, hs + 4 * (i - 1), hs + 4 * i,
                                         beta_p, scal, N);
      if (v2) {
        cavity_csr<<<gS4, NBLK, 0, stream>>>(srcOf, revslot, em_csr, P, Fc, Fn,
                                             hs + 4 * i, beta_p, scal, E);
        float* tmp = Fc; Fc = Fn; Fn = tmp;
      } else {
        edge_fuse<<<gE, NBLK, 0, stream>>>(ei, em, P, F_A, hs + 4 * i, beta_p,
                                           scal, E, Eh);
      }
    }
  }
  node_post_final<<<gN, NBLK, 0, stream>>>(P, deg, hs + 40, beta_p, scal,
                                           out_s, scal + 2, N);
  edge_final<<<512, NBLK, 0, stream>>>(ei, w, out_s, scal + 1, E, Eh);
  finalize<<<1, 1, 0, stream>>>(scal, out_s + (size_t)N * QD);
}

// Round 13
// 1728.470 us; speedup vs baseline: 1.1307x; 1.1272x over previous
//
#include <hip/hip_runtime.h>

// CD_BP_Net R13: R8 structure (proven 1719us) + 2-pair edge_fuse.
//  Evidence-consolidated model: every layout pays ~3.2M random 64B
//  line-requests/iter (the dst-grouping permutation); fabric serves
//  ~55G req/s -> ~58us/iter irreducible. R12's CSR-residency only moved
//  the permutation (cavity F_old[revslot]) and added 233us csrmeta. Revert.
//  Single change vs R8: edge_fuse processes 2 strided pairs/thread
//  (batched independent loads; P-request MLP x2).

#define NBLK 256
#define QD 4
#define SENT 0x7fffffff

__device__ __forceinline__ float wave_red(float v) {
#pragma unroll
  for (int o = 32; o > 0; o >>= 1) v += __shfl_down(v, o, 64);
  return v;
}

__device__ __forceinline__ void atomicMulF(float* addr, float val) {
  unsigned int old = __float_as_uint(*addr), assumed;
  do {
    assumed = old;
    float nv = __uint_as_float(assumed) * val;
    old = atomicCAS((unsigned int*)addr, assumed, __float_as_uint(nv));
  } while (old != assumed);
}

// ---- CSR build ----------------------------------------------------------
__global__ void hist_rank(const int* __restrict__ ei, int* __restrict__ cnt,
                          int* __restrict__ rank, int E) {
  int G = gridDim.x * blockDim.x;
  int e[8], d[8];
#pragma unroll
  for (int j = 0; j < 8; ++j) {
    e[j] = blockIdx.x * blockDim.x + threadIdx.x + j * G;
    d[j] = (e[j] < E) ? ei[E + e[j]] : 0;
  }
#pragma unroll
  for (int j = 0; j < 8; ++j)
    if (e[j] < E) rank[e[j]] = atomicAdd(&cnt[d[j]], 1);
}

__global__ void scanA(const int* __restrict__ cnt, int* __restrict__ out,
                      int* __restrict__ bsum, int N) {
  __shared__ int lds[256];
  int base = blockIdx.x * 1024 + threadIdx.x * 4;
  int v0 = (base + 0 < N) ? cnt[base + 0] : 0;
  int v1 = (base + 1 < N) ? cnt[base + 1] : 0;
  int v2 = (base + 2 < N) ? cnt[base + 2] : 0;
  int v3 = (base + 3 < N) ? cnt[base + 3] : 0;
  lds[threadIdx.x] = v0 + v1 + v2 + v3;
  __syncthreads();
  for (int off = 1; off < 256; off <<= 1) {
    int x = (threadIdx.x >= off) ? lds[threadIdx.x - off] : 0;
    __syncthreads();
    if (threadIdx.x >= off) lds[threadIdx.x] += x;
    __syncthreads();
  }
  int excl = (threadIdx.x == 0) ? 0 : lds[threadIdx.x - 1];
  if (threadIdx.x == 255) bsum[blockIdx.x] = lds[255];
  if (base + 0 < N) out[base + 0] = excl;
  if (base + 1 < N) out[base + 1] = excl + v0;
  if (base + 2 < N) out[base + 2] = excl + v0 + v1;
  if (base + 3 < N) out[base + 3] = excl + v0 + v1 + v2;
}

__global__ void scanB(int* __restrict__ bsum, int NB) {
  __shared__ int lds[256];
  int v = (threadIdx.x < NB) ? bsum[threadIdx.x] : 0;
  lds[threadIdx.x] = v;
  __syncthreads();
  for (int off = 1; off < 256; off <<= 1) {
    int x = (threadIdx.x >= off) ? lds[threadIdx.x - off] : 0;
    __syncthreads();
    if (threadIdx.x >= off) lds[threadIdx.x] += x;
    __syncthreads();
  }
  int excl = (threadIdx.x == 0) ? 0 : lds[threadIdx.x - 1];
  if (threadIdx.x < NB) bsum[threadIdx.x] = excl;
}

__global__ void scanC(int* __restrict__ rowStart, const int* __restrict__ bsum,
                      int N, int E) {
  int i = blockIdx.x * blockDim.x + threadIdx.x;
  if (i < N) rowStart[i] += bsum[i >> 10];
  if (i == 0) rowStart[N] = E;
}

__global__ void scatter_inc(const int* __restrict__ ei, const int* __restrict__ rowStart,
                            const int* __restrict__ rank, int* __restrict__ inc, int E) {
  int G = gridDim.x * blockDim.x;
#pragma unroll
  for (int j = 0; j < 4; ++j) {
    int e = blockIdx.x * blockDim.x + threadIdx.x + j * G;
    if (e < E) {
      int d = ei[E + e];
      inc[rowStart[d] + rank[e]] = e;
    }
  }
}

__global__ void build_nodeOf(const int* __restrict__ rowStart, int* __restrict__ nodeOf,
                             int N) {
  int n = blockIdx.x * blockDim.x + threadIdx.x;
  if (n >= N) return;
  int s = rowStart[n], e = rowStart[n + 1];
  for (int k = s; k < e; ++k) nodeOf[k] = n;
}

// ---- setup: em, F0 = 1 + psi0*em, two_m (block-reduced) ----------------
__global__ void setup_pairs(const float* __restrict__ w, const float* __restrict__ msg,
                            const float* __restrict__ beta_p, float* __restrict__ F,
                            float* __restrict__ em_buf, double* __restrict__ two_m,
                            int Eh) {
  __shared__ float blk[4];
  int t = blockIdx.x * blockDim.x + threadIdx.x;
  float tw = 0.f;
  if (t < Eh) {
    float beta = beta_p[0];
    float wv = w[t];  // == w[t+Eh]
    tw = 2.f * wv;
    float em = expm1f(beta * wv);
    em_buf[t] = em;
    float4 m1 = *reinterpret_cast<const float4*>(&msg[(size_t)t * QD]);
    float4 m2 = *reinterpret_cast<const float4*>(&msg[((size_t)t + Eh) * QD]);
    float i1 = em / (m1.x + m1.y + m1.z + m1.w);
    float i2 = em / (m2.x + m2.y + m2.z + m2.w);
    float4 F1 = make_float4(fmaf(m1.x, i1, 1.f), fmaf(m1.y, i1, 1.f),
                            fmaf(m1.z, i1, 1.f), fmaf(m1.w, i1, 1.f));
    float4 F2 = make_float4(fmaf(m2.x, i2, 1.f), fmaf(m2.y, i2, 1.f),
                            fmaf(m2.z, i2, 1.f), fmaf(m2.w, i2, 1.f));
    *reinterpret_cast<float4*>(&F[(size_t)t * QD]) = F1;
    *reinterpret_cast<float4*>(&F[((size_t)t + Eh) * QD]) = F2;
  }
  tw = wave_red(tw);
  int wid = threadIdx.x >> 6;
  if ((threadIdx.x & 63) == 0) blk[wid] = tw;
  __syncthreads();
  if (threadIdx.x == 0)
    atomicAdd(two_m, (double)(blk[0] + blk[1] + blk[2] + blk[3]));
}

__global__ void fillP(float* __restrict__ P, int n4) {
  int i = blockIdx.x * blockDim.x + threadIdx.x;
  if (i < n4) P[i] = 1.0f;
}

// ---- segmented gather: NW windows of 64 slots per wave ------------------
template <int NC, bool PROD, int NW>
__global__ void gather_seg(const int* __restrict__ inc, const int* __restrict__ nodeOf,
                           const float* __restrict__ src, float* __restrict__ out,
                           int E) {
  const int lane = threadIdx.x & 63;
  const int wid = threadIdx.x >> 6;
  const long long base = ((long long)blockIdx.x * (blockDim.x >> 6) + wid) * (NW * 64);
  if (base >= E) return;
  const float IDENT = PROD ? 1.f : 0.f;
  int n[NW], idx[NW];
  float v[NW][NC];
#pragma unroll
  for (int w = 0; w < NW; ++w) {
    long long k = base + w * 64 + lane;
    n[w] = (k < E) ? nodeOf[k] : SENT;
    idx[w] = (k < E) ? inc[k] : 0;
  }
#pragma unroll
  for (int w = 0; w < NW; ++w) {
    long long k = base + w * 64 + lane;
    if (k < E) {
      if constexpr (NC == 4) {
        float4 t = *reinterpret_cast<const float4*>(&src[(size_t)idx[w] * 4]);
        v[w][0] = t.x; v[w][1] = t.y; v[w][2] = t.z; v[w][3] = t.w;
      } else {
        v[w][0] = src[idx[w]];
      }
    } else {
#pragma unroll
      for (int c = 0; c < NC; ++c) v[w][c] = IDENT;
    }
  }
  int n00 = __shfl(n[0], 0, 64);
  int prevn = (base > 0) ? nodeOf[base - 1] : -1;
  const int incomplete = (prevn == n00) ? n00 : -1;
  int nwf[NW];
#pragma unroll
  for (int w = 0; w < NW - 1; ++w) nwf[w] = __shfl(n[w + 1], 0, 64);
  nwf[NW - 1] = (base + NW * 64 < E) ? nodeOf[base + NW * 64] : -1;

  float cv[NC];
#pragma unroll
  for (int c = 0; c < NC; ++c) cv[c] = IDENT;
  int cn = -1;
#pragma unroll
  for (int w = 0; w < NW; ++w) {
    int nn = n[w];
#pragma unroll
    for (int d = 1; d < 64; d <<= 1) {
      int pn = __shfl_up(nn, d, 64);
      float pv[NC];
#pragma unroll
      for (int c = 0; c < NC; ++c) pv[c] = __shfl_up(v[w][c], d, 64);
      if (lane >= d && pn == nn) {
#pragma unroll
        for (int c = 0; c < NC; ++c) {
          if constexpr (PROD) v[w][c] *= pv[c]; else v[w][c] += pv[c];
        }
      }
    }
    if (nn == cn) {
#pragma unroll
      for (int c = 0; c < NC; ++c) {
        if constexpr (PROD) v[w][c] *= cv[c]; else v[w][c] += cv[c];
      }
    }
    int nnext = __shfl_down(nn, 1, 64);
    if (lane == 63) nnext = nwf[w];
    bool segend = (nn != SENT) && (nnext != nn);
    if (segend) {
      if (nn == incomplete) {
#pragma unroll
        for (int c = 0; c < NC; ++c) {
          if constexpr (PROD) atomicMulF(&out[(size_t)nn * NC + c], v[w][c]);
          else atomicAdd(&out[(size_t)nn * NC + c], v[w][c]);
        }
      } else {
        if constexpr (NC == 4) {
          *reinterpret_cast<float4*>(&out[(size_t)nn * 4]) =
              make_float4(v[w][0], v[w][1], v[w][2], v[w][3]);
        } else {
          out[nn] = v[w][0];
        }
      }
    }
    int last_n = __shfl(nn, 63, 64);
    float lv[NC];
#pragma unroll
    for (int c = 0; c < NC; ++c) lv[c] = __shfl(v[w][c], 63, 64);
    bool last_end = (nwf[w] != last_n) || (last_n == SENT);
    if (last_end) {
      cn = -1;
#pragma unroll
      for (int c = 0; c < NC; ++c) cv[c] = IDENT;
    } else {
      cn = last_n;
#pragma unroll
      for (int c = 0; c < NC; ++c) cv[c] = lv[c];
    }
  }
  if (cn != -1 && lane == 0) {
#pragma unroll
    for (int c = 0; c < NC; ++c) {
      if constexpr (PROD) atomicMulF(&out[(size_t)cn * NC + c], cv[c]);
      else atomicAdd(&out[(size_t)cn * NC + c], cv[c]);
    }
  }
}

// ---- node: marg = eh*P/sum; hsum_new += deg*marg (block-reduced) -------
__global__ void node_post(const float* __restrict__ P, const float* __restrict__ deg,
                          const double* __restrict__ hsum_prev, double* __restrict__ hsum_new,
                          const float* __restrict__ beta_p, const double* __restrict__ two_m,
                          int N) {
  __shared__ float blk[4][4];
  int n = blockIdx.x * blockDim.x + threadIdx.x;
  float scale = -beta_p[0] / (float)two_m[0];
  float e0 = expf(scale * (float)hsum_prev[0]);
  float e1 = expf(scale * (float)hsum_prev[1]);
  float e2 = expf(scale * (float)hsum_prev[2]);
  float e3 = expf(scale * (float)hsum_prev[3]);
  float a0 = 0.f, a1 = 0.f, a2 = 0.f, a3 = 0.f;
  if (n < N) {
    float4 Pv = *reinterpret_cast<const float4*>(&P[(size_t)n * QD]);
    float m0 = e0 * Pv.x, m1 = e1 * Pv.y, m2 = e2 * Pv.z, m3 = e3 * Pv.w;
    float dinv = deg[n] / (m0 + m1 + m2 + m3);
    a0 = m0 * dinv; a1 = m1 * dinv; a2 = m2 * dinv; a3 = m3 * dinv;
  }
  a0 = wave_red(a0); a1 = wave_red(a1); a2 = wave_red(a2); a3 = wave_red(a3);
  int wid = threadIdx.x >> 6;
  if ((threadIdx.x & 63) == 0) {
    blk[wid][0] = a0; blk[wid][1] = a1; blk[wid][2] = a2; blk[wid][3] = a3;
  }
  __syncthreads();
  if (threadIdx.x < 4) {
    float s = blk[0][threadIdx.x] + blk[1][threadIdx.x] + blk[2][threadIdx.x] +
              blk[3][threadIdx.x];
    atomicAdd(&hsum_new[threadIdx.x], (double)s);
  }
}

__global__ void node_post_final(const float* __restrict__ P, const float* __restrict__ deg,
                                const double* __restrict__ hsum, const float* __restrict__ beta_p,
                                const double* __restrict__ two_m, float* __restrict__ out_s,
                                double* __restrict__ comm_raw, int N) {
  __shared__ float blk[4][4];
  int n = blockIdx.x * blockDim.x + threadIdx.x;
  float scale = -beta_p[0] / (float)two_m[0];
  float e0 = expf(scale * (float)hsum[0]);
  float e1 = expf(scale * (float)hsum[1]);
  float e2 = expf(scale * (float)hsum[2]);
  float e3 = expf(scale * (float)hsum[3]);
  float a0 = 0.f, a1 = 0.f, a2 = 0.f, a3 = 0.f;
  if (n < N) {
    float4 Pv = *reinterpret_cast<const float4*>(&P[(size_t)n * QD]);
    float m0 = e0 * Pv.x, m1 = e1 * Pv.y, m2 = e2 * Pv.z, m3 = e3 * Pv.w;
    float inv = 1.f / (m0 + m1 + m2 + m3);
    float4 s = make_float4(m0 * inv, m1 * inv, m2 * inv, m3 * inv);
    *reinterpret_cast<float4*>(&out_s[(size_t)n * QD]) = s;
    float d = deg[n];
    a0 = d * s.x; a1 = d * s.y; a2 = d * s.z; a3 = d * s.w;
  }
  a0 = wave_red(a0); a1 = wave_red(a1); a2 = wave_red(a2); a3 = wave_red(a3);
  int wid = threadIdx.x >> 6;
  if ((threadIdx.x & 63) == 0) {
    blk[wid][0] = a0; blk[wid][1] = a1; blk[wid][2] = a2; blk[wid][3] = a3;
  }
  __syncthreads();
  if (threadIdx.x < 4) {
    float s = blk[0][threadIdx.x] + blk[1][threadIdx.x] + blk[2][threadIdx.x] +
              blk[3][threadIdx.x];
    atomicAdd(&comm_raw[threadIdx.x], (double)s);
  }
}

// ---- cavity update, product form, 2 strided pairs/thread ---------------
__global__ void edge_fuse(const int* __restrict__ ei, const float* __restrict__ em_buf,
                          const float* __restrict__ P, float* __restrict__ F,
                          const double* __restrict__ hsum, const float* __restrict__ beta_p,
                          const double* __restrict__ two_m, int E, int Eh) {
  int G = gridDim.x * blockDim.x;
  int t0 = blockIdx.x * blockDim.x + threadIdx.x;
  int t1 = t0 + G;
  float scale = -beta_p[0] / (float)two_m[0];
  float e0 = expf(scale * (float)hsum[0]);
  float e1 = expf(scale * (float)hsum[1]);
  float e2 = expf(scale * (float)hsum[2]);
  float e3 = expf(scale * (float)hsum[3]);
  int s1a = 0, d1a = 0, s1b = 0, d1b = 0;
  float ema = 0.f, emb = 0.f;
  if (t0 < Eh) { s1a = ei[t0]; d1a = ei[E + t0]; ema = em_buf[t0]; }
  if (t1 < Eh) { s1b = ei[t1]; d1b = ei[E + t1]; emb = em_buf[t1]; }
  float4 F1a, F2a, F1b, F2b, Psa, Pda, Psb, Pdb;
  if (t0 < Eh) {
    F1a = *reinterpret_cast<const float4*>(&F[(size_t)t0 * QD]);
    F2a = *reinterpret_cast<const float4*>(&F[((size_t)t0 + Eh) * QD]);
    Psa = *reinterpret_cast<const float4*>(&P[(size_t)s1a * QD]);
    Pda = *reinterpret_cast<const float4*>(&P[(size_t)d1a * QD]);
  }
  if (t1 < Eh) {
    F1b = *reinterpret_cast<const float4*>(&F[(size_t)t1 * QD]);
    F2b = *reinterpret_cast<const float4*>(&F[((size_t)t1 + Eh) * QD]);
    Psb = *reinterpret_cast<const float4*>(&P[(size_t)s1b * QD]);
    Pdb = *reinterpret_cast<const float4*>(&P[(size_t)d1b * QD]);
  }
#define CAV(Fr, Pn, em, dstp)                                            \
  {                                                                      \
    float a01 = (Fr).x * (Fr).y, a23 = (Fr).z * (Fr).w;                  \
    float x0 = (Fr).y * a23, x1 = (Fr).x * a23;                          \
    float x2 = a01 * (Fr).w, x3 = a01 * (Fr).z;                          \
    float n0 = e0 * (Pn).x * x0, n1 = e1 * (Pn).y * x1;                  \
    float n2 = e2 * (Pn).z * x2, n3 = e3 * (Pn).w * x3;                  \
    float tt = (em) / (n0 + n1 + n2 + n3);                               \
    *reinterpret_cast<float4*>(dstp) =                                   \
        make_float4(fmaf(n0, tt, 1.f), fmaf(n1, tt, 1.f),                \
                    fmaf(n2, tt, 1.f), fmaf(n3, tt, 1.f));               \
  }
  if (t0 < Eh) {
    CAV(F2a, Psa, ema, &F[(size_t)t0 * QD]);
    CAV(F1a, Pda, ema, &F[((size_t)t0 + Eh) * QD]);
  }
  if (t1 < Eh) {
    CAV(F2b, Psb, emb, &F[(size_t)t1 * QD]);
    CAV(F1b, Pdb, emb, &F[((size_t)t1 + Eh) * QD]);
  }
#undef CAV
}

__global__ void edge_final(const int* __restrict__ ei, const float* __restrict__ w,
                           const float* __restrict__ out_s,
                           double* __restrict__ link_raw, int E, int Eh) {
  __shared__ float blk[4];
  int G = gridDim.x * blockDim.x;
  float c = 0.f;
  for (int t = blockIdx.x * blockDim.x + threadIdx.x; t < Eh; t += G) {
    int s1 = ei[t];
    int d1 = ei[E + t];
    float4 a = *reinterpret_cast<const float4*>(&out_s[(size_t)s1 * QD]);
    float4 b = *reinterpret_cast<const float4*>(&out_s[(size_t)d1 * QD]);
    float dot = a.x * b.x + a.y * b.y + a.z * b.z + a.w * b.w;
    c += 2.f * w[t] * dot;
  }
  c = wave_red(c);
  int wid = threadIdx.x >> 6;
  if ((threadIdx.x & 63) == 0) blk[wid] = c;
  __syncthreads();
  if (threadIdx.x == 0)
    atomicAdd(link_raw, (double)(blk[0] + blk[1] + blk[2] + blk[3]));
}

__global__ void finalize(const double* __restrict__ scal, float* __restrict__ out_q) {
  double tm = scal[0];
  double link = scal[1] / tm;
  double acc = 0.0;
#pragma unroll
  for (int k = 0; k < QD; ++k) {
    double c = scal[2 + k] / tm;
    acc += c * c;
  }
  out_q[0] = (float)(link - acc);
}

extern "C" void kernel_launch(void* const* d_in, const int* in_sizes, int n_in,
                              void* d_out, int out_size, void* d_ws, size_t ws_size,
                              hipStream_t stream) {
  const int* ei = (const int*)d_in[0];         // [2,E] int32
  const float* w = (const float*)d_in[1];      // [E]
  const float* msg = (const float*)d_in[2];    // [E,4]
  const float* beta_p = (const float*)d_in[3]; // scalar

  const int E = in_sizes[1];
  const int Eh = E / 2;
  const int N = (out_size - 1) / QD;

  // ws: scal [0]=two_m [1]=link [2..5]=comm [6+4i..]=hsum (i=0..10)
  char* p = (char*)d_ws;
  double* scal = (double*)p;
  size_t off = 512;
  int* cnt = (int*)(p + off); off += (size_t)N * 4;
  int* rowStart = (int*)(p + off); off += (size_t)(N + 1) * 4;
  off = (off + 127) & ~(size_t)127;
  int* bsum = (int*)(p + off); off += 1024;
  int* inc = (int*)(p + off); off += (size_t)E * 4;
  float* deg = (float*)(p + off); off += (size_t)N * 4;
  off = (off + 15) & ~(size_t)15;
  float* P = (float*)(p + off); off += (size_t)N * QD * 4;
  float* em = (float*)(p + off); off += (size_t)Eh * 4;
  off = (off + 15) & ~(size_t)15;
  float* F = (float*)(p + off); off += (size_t)E * QD * 4;
  int* rank = (int*)F;  // alias: rank dead before F is first written
  int* nodeOf = (int*)(p + off); off += (size_t)E * 4;
  (void)ws_size;

  double* hs = scal + 6;
  const int gE = (Eh + NBLK - 1) / NBLK;
  const int gE2 = (Eh / 2 + NBLK - 1) / NBLK + 1;
  const int gN = (N + NBLK - 1) / NBLK;
  const int gH = (E + NBLK * 8 - 1) / (NBLK * 8);
  const int gSc = (E + NBLK * 4 - 1) / (NBLK * 4);
  const int gWp = (E + 2047) / 2048;   // gather_seg<4,PROD,8>: 2048 slots/block
  const int gWd = (E + 1023) / 1024;   // gather_seg<1,SUM,4>:  1024 slots/block
  const int gF = (4 * N + NBLK - 1) / NBLK;
  const int NBscan = (N + 1023) / 1024;

  hipMemsetAsync(scal, 0, 512, stream);
  hipMemsetAsync(cnt, 0, (size_t)N * 4, stream);
  hipMemsetAsync(deg, 0, (size_t)N * 4, stream);

  hist_rank<<<gH, NBLK, 0, stream>>>(ei, cnt, rank, E);
  scanA<<<NBscan, 256, 0, stream>>>(cnt, rowStart, bsum, N);
  scanB<<<1, 256, 0, stream>>>(bsum, NBscan);
  scanC<<<(N + NBLK) / NBLK, NBLK, 0, stream>>>(rowStart, bsum, N, E);
  scatter_inc<<<gSc, NBLK, 0, stream>>>(ei, rowStart, rank, inc, E);
  build_nodeOf<<<gN, NBLK, 0, stream>>>(rowStart, nodeOf, N);

  setup_pairs<<<gE, NBLK, 0, stream>>>(w, msg, beta_p, F, em, scal, Eh);
  gather_seg<1, false, 4><<<gWd, NBLK, 0, stream>>>(inc, nodeOf, w, deg, E);

  float* out_s = (float*)d_out;
  for (int i = 1; i <= 11; ++i) {
    fillP<<<gF, NBLK, 0, stream>>>(P, 4 * N);
    gather_seg<4, true, 8><<<gWp, NBLK, 0, stream>>>(inc, nodeOf, F, P, E);
    if (i <= 10) {
      node_post<<<gN, NBLK, 0, stream>>>(P, deg, hs + 4 * (i - 1), hs + 4 * i,
                                         beta_p, scal, N);
      edge_fuse<<<gE2, NBLK, 0, stream>>>(ei, em, P, F, hs + 4 * i, beta_p, scal, E, Eh);
    }
  }
  node_post_final<<<gN, NBLK, 0, stream>>>(P, deg, hs + 40, beta_p, scal,
                                           out_s, scal + 2, N);
  edge_final<<<512, NBLK, 0, stream>>>(ei, w, out_s, scal + 1, E, Eh);
  finalize<<<1, 1, 0, stream>>>(scal, out_s + (size_t)N * QD);
}

// Round 14
// 1635.663 us; speedup vs baseline: 1.1948x; 1.0567x over previous
//
#include <hip/hip_runtime.h>
#include <hip/hip_fp16.h>

// CD_BP_Net R14: R13 structure + fp16 edge state (HALVE the random-line floor).
//  Edge state stored as G = psi*em = F-1 in [0,0.86], 4xfp16 = 8B/edge
//  (25.6MB buffer, was 51.2MB fp32). Random gather line-count halves:
//  FETCH 218->~110MB. F = 1+G reconstructed in fp32; storing the OFFSET
//  keeps F's error at ~5e-5 for typical G~0.1 (vs 5e-4 storing F direct).
//  Everything else identical to R13 (proven 1729us).

#define NBLK 256
#define QD 4
#define SENT 0x7fffffff

__device__ __forceinline__ float wave_red(float v) {
#pragma unroll
  for (int o = 32; o > 0; o >>= 1) v += __shfl_down(v, o, 64);
  return v;
}

__device__ __forceinline__ void atomicMulF(float* addr, float val) {
  unsigned int old = __float_as_uint(*addr), assumed;
  do {
    assumed = old;
    float nv = __uint_as_float(assumed) * val;
    old = atomicCAS((unsigned int*)addr, assumed, __float_as_uint(nv));
  } while (old != assumed);
}

// G (4xfp16) pack/unpack: one uint2 = 8B per edge
__device__ __forceinline__ void g_unpack(uint2 raw, float* g) {
  __half2 h0 = *reinterpret_cast<const __half2*>(&raw.x);
  __half2 h1 = *reinterpret_cast<const __half2*>(&raw.y);
  float2 a = __half22float2(h0), b = __half22float2(h1);
  g[0] = a.x; g[1] = a.y; g[2] = b.x; g[3] = b.y;
}
__device__ __forceinline__ uint2 g_pack(float g0, float g1, float g2, float g3) {
  __half2 h0 = __floats2half2_rn(g0, g1);
  __half2 h1 = __floats2half2_rn(g2, g3);
  uint2 raw;
  raw.x = *reinterpret_cast<unsigned*>(&h0);
  raw.y = *reinterpret_cast<unsigned*>(&h1);
  return raw;
}

// ---- CSR build ----------------------------------------------------------
__global__ void hist_rank(const int* __restrict__ ei, int* __restrict__ cnt,
                          int* __restrict__ rank, int E) {
  int G = gridDim.x * blockDim.x;
  int e[8], d[8];
#pragma unroll
  for (int j = 0; j < 8; ++j) {
    e[j] = blockIdx.x * blockDim.x + threadIdx.x + j * G;
    d[j] = (e[j] < E) ? ei[E + e[j]] : 0;
  }
#pragma unroll
  for (int j = 0; j < 8; ++j)
    if (e[j] < E) rank[e[j]] = atomicAdd(&cnt[d[j]], 1);
}

__global__ void scanA(const int* __restrict__ cnt, int* __restrict__ out,
                      int* __restrict__ bsum, int N) {
  __shared__ int lds[256];
  int base = blockIdx.x * 1024 + threadIdx.x * 4;
  int v0 = (base + 0 < N) ? cnt[base + 0] : 0;
  int v1 = (base + 1 < N) ? cnt[base + 1] : 0;
  int v2 = (base + 2 < N) ? cnt[base + 2] : 0;
  int v3 = (base + 3 < N) ? cnt[base + 3] : 0;
  lds[threadIdx.x] = v0 + v1 + v2 + v3;
  __syncthreads();
  for (int off = 1; off < 256; off <<= 1) {
    int x = (threadIdx.x >= off) ? lds[threadIdx.x - off] : 0;
    __syncthreads();
    if (threadIdx.x >= off) lds[threadIdx.x] += x;
    __syncthreads();
  }
  int excl = (threadIdx.x == 0) ? 0 : lds[threadIdx.x - 1];
  if (threadIdx.x == 255) bsum[blockIdx.x] = lds[255];
  if (base + 0 < N) out[base + 0] = excl;
  if (base + 1 < N) out[base + 1] = excl + v0;
  if (base + 2 < N) out[base + 2] = excl + v0 + v1;
  if (base + 3 < N) out[base + 3] = excl + v0 + v1 + v2;
}

__global__ void scanB(int* __restrict__ bsum, int NB) {
  __shared__ int lds[256];
  int v = (threadIdx.x < NB) ? bsum[threadIdx.x] : 0;
  lds[threadIdx.x] = v;
  __syncthreads();
  for (int off = 1; off < 256; off <<= 1) {
    int x = (threadIdx.x >= off) ? lds[threadIdx.x - off] : 0;
    __syncthreads();
    if (threadIdx.x >= off) lds[threadIdx.x] += x;
    __syncthreads();
  }
  int excl = (threadIdx.x == 0) ? 0 : lds[threadIdx.x - 1];
  if (threadIdx.x < NB) bsum[threadIdx.x] = excl;
}

__global__ void scanC(int* __restrict__ rowStart, const int* __restrict__ bsum,
                      int N, int E) {
  int i = blockIdx.x * blockDim.x + threadIdx.x;
  if (i < N) rowStart[i] += bsum[i >> 10];
  if (i == 0) rowStart[N] = E;
}

__global__ void scatter_inc(const int* __restrict__ ei, const int* __restrict__ rowStart,
                            const int* __restrict__ rank, int* __restrict__ inc, int E) {
  int G = gridDim.x * blockDim.x;
#pragma unroll
  for (int j = 0; j < 4; ++j) {
    int e = blockIdx.x * blockDim.x + threadIdx.x + j * G;
    if (e < E) {
      int d = ei[E + e];
      inc[rowStart[d] + rank[e]] = e;
    }
  }
}

__global__ void build_nodeOf(const int* __restrict__ rowStart, int* __restrict__ nodeOf,
                             int N) {
  int n = blockIdx.x * blockDim.x + threadIdx.x;
  if (n >= N) return;
  int s = rowStart[n], e = rowStart[n + 1];
  for (int k = s; k < e; ++k) nodeOf[k] = n;
}

// ---- setup: em, G0 = psi0*em (fp16x4), two_m (block-reduced) -----------
__global__ void setup_pairs(const float* __restrict__ w, const float* __restrict__ msg,
                            const float* __restrict__ beta_p, uint2* __restrict__ Gu,
                            float* __restrict__ em_buf, double* __restrict__ two_m,
                            int Eh) {
  __shared__ float blk[4];
  int t = blockIdx.x * blockDim.x + threadIdx.x;
  float tw = 0.f;
  if (t < Eh) {
    float beta = beta_p[0];
    float wv = w[t];  // == w[t+Eh]
    tw = 2.f * wv;
    float em = expm1f(beta * wv);
    em_buf[t] = em;
    float4 m1 = *reinterpret_cast<const float4*>(&msg[(size_t)t * QD]);
    float4 m2 = *reinterpret_cast<const float4*>(&msg[((size_t)t + Eh) * QD]);
    float i1 = em / (m1.x + m1.y + m1.z + m1.w);
    float i2 = em / (m2.x + m2.y + m2.z + m2.w);
    Gu[t] = g_pack(m1.x * i1, m1.y * i1, m1.z * i1, m1.w * i1);
    Gu[(size_t)t + Eh] = g_pack(m2.x * i2, m2.y * i2, m2.z * i2, m2.w * i2);
  }
  tw = wave_red(tw);
  int wid = threadIdx.x >> 6;
  if ((threadIdx.x & 63) == 0) blk[wid] = tw;
  __syncthreads();
  if (threadIdx.x == 0)
    atomicAdd(two_m, (double)(blk[0] + blk[1] + blk[2] + blk[3]));
}

__global__ void fillP(float* __restrict__ P, int n4) {
  int i = blockIdx.x * blockDim.x + threadIdx.x;
  if (i < n4) P[i] = 1.0f;
}

// ---- segmented gather: NW windows of 64 slots per wave ------------------
// HALFIN: src is uint2* (4xfp16 G per edge); value = 1+G. Else fp32 src.
template <int NC, bool PROD, int NW, bool HALFIN>
__global__ void gather_seg(const int* __restrict__ inc, const int* __restrict__ nodeOf,
                           const void* __restrict__ srcv, float* __restrict__ out,
                           int E) {
  const int lane = threadIdx.x & 63;
  const int wid = threadIdx.x >> 6;
  const long long base = ((long long)blockIdx.x * (blockDim.x >> 6) + wid) * (NW * 64);
  if (base >= E) return;
  const float IDENT = PROD ? 1.f : 0.f;
  int n[NW], idx[NW];
  float v[NW][NC];
#pragma unroll
  for (int w = 0; w < NW; ++w) {
    long long k = base + w * 64 + lane;
    n[w] = (k < E) ? nodeOf[k] : SENT;
    idx[w] = (k < E) ? inc[k] : 0;
  }
#pragma unroll
  for (int w = 0; w < NW; ++w) {
    long long k = base + w * 64 + lane;
    if (k < E) {
      if constexpr (HALFIN) {
        uint2 raw = reinterpret_cast<const uint2*>(srcv)[idx[w]];
        float g[4];
        g_unpack(raw, g);
#pragma unroll
        for (int c = 0; c < 4; ++c) v[w][c] = 1.f + g[c];
      } else if constexpr (NC == 4) {
        float4 t = *reinterpret_cast<const float4*>(
            &reinterpret_cast<const float*>(srcv)[(size_t)idx[w] * 4]);
        v[w][0] = t.x; v[w][1] = t.y; v[w][2] = t.z; v[w][3] = t.w;
      } else {
        v[w][0] = reinterpret_cast<const float*>(srcv)[idx[w]];
      }
    } else {
#pragma unroll
      for (int c = 0; c < NC; ++c) v[w][c] = IDENT;
    }
  }
  int n00 = __shfl(n[0], 0, 64);
  int prevn = (base > 0) ? nodeOf[base - 1] : -1;
  const int incomplete = (prevn == n00) ? n00 : -1;
  int nwf[NW];
#pragma unroll
  for (int w = 0; w < NW - 1; ++w) nwf[w] = __shfl(n[w + 1], 0, 64);
  nwf[NW - 1] = (base + NW * 64 < E) ? nodeOf[base + NW * 64] : -1;

  float cv[NC];
#pragma unroll
  for (int c = 0; c < NC; ++c) cv[c] = IDENT;
  int cn = -1;
#pragma unroll
  for (int w = 0; w < NW; ++w) {
    int nn = n[w];
#pragma unroll
    for (int d = 1; d < 64; d <<= 1) {
      int pn = __shfl_up(nn, d, 64);
      float pv[NC];
#pragma unroll
      for (int c = 0; c < NC; ++c) pv[c] = __shfl_up(v[w][c], d, 64);
      if (lane >= d && pn == nn) {
#pragma unroll
        for (int c = 0; c < NC; ++c) {
          if constexpr (PROD) v[w][c] *= pv[c]; else v[w][c] += pv[c];
        }
      }
    }
    if (nn == cn) {
#pragma unroll
      for (int c = 0; c < NC; ++c) {
        if constexpr (PROD) v[w][c] *= cv[c]; else v[w][c] += cv[c];
      }
    }
    int nnext = __shfl_down(nn, 1, 64);
    if (lane == 63) nnext = nwf[w];
    bool segend = (nn != SENT) && (nnext != nn);
    if (segend) {
      if (nn == incomplete) {
#pragma unroll
        for (int c = 0; c < NC; ++c) {
          if constexpr (PROD) atomicMulF(&out[(size_t)nn * NC + c], v[w][c]);
          else atomicAdd(&out[(size_t)nn * NC + c], v[w][c]);
        }
      } else {
        if constexpr (NC == 4) {
          *reinterpret_cast<float4*>(&out[(size_t)nn * 4]) =
              make_float4(v[w][0], v[w][1], v[w][2], v[w][3]);
        } else {
          out[nn] = v[w][0];
        }
      }
    }
    int last_n = __shfl(nn, 63, 64);
    float lv[NC];
#pragma unroll
    for (int c = 0; c < NC; ++c) lv[c] = __shfl(v[w][c], 63, 64);
    bool last_end = (nwf[w] != last_n) || (last_n == SENT);
    if (last_end) {
      cn = -1;
#pragma unroll
      for (int c = 0; c < NC; ++c) cv[c] = IDENT;
    } else {
      cn = last_n;
#pragma unroll
      for (int c = 0; c < NC; ++c) cv[c] = lv[c];
    }
  }
  if (cn != -1 && lane == 0) {
#pragma unroll
    for (int c = 0; c < NC; ++c) {
      if constexpr (PROD) atomicMulF(&out[(size_t)cn * NC + c], cv[c]);
      else atomicAdd(&out[(size_t)cn * NC + c], cv[c]);
    }
  }
}

// ---- node: marg = eh*P/sum; hsum_new += deg*marg (block-reduced) -------
__global__ void node_post(const float* __restrict__ P, const float* __restrict__ deg,
                          const double* __restrict__ hsum_prev, double* __restrict__ hsum_new,
                          const float* __restrict__ beta_p, const double* __restrict__ two_m,
                          int N) {
  __shared__ float blk[4][4];
  int n = blockIdx.x * blockDim.x + threadIdx.x;
  float scale = -beta_p[0] / (float)two_m[0];
  float e0 = expf(scale * (float)hsum_prev[0]);
  float e1 = expf(scale * (float)hsum_prev[1]);
  float e2 = expf(scale * (float)hsum_prev[2]);
  float e3 = expf(scale * (float)hsum_prev[3]);
  float a0 = 0.f, a1 = 0.f, a2 = 0.f, a3 = 0.f;
  if (n < N) {
    float4 Pv = *reinterpret_cast<const float4*>(&P[(size_t)n * QD]);
    float m0 = e0 * Pv.x, m1 = e1 * Pv.y, m2 = e2 * Pv.z, m3 = e3 * Pv.w;
    float dinv = deg[n] / (m0 + m1 + m2 + m3);
    a0 = m0 * dinv; a1 = m1 * dinv; a2 = m2 * dinv; a3 = m3 * dinv;
  }
  a0 = wave_red(a0); a1 = wave_red(a1); a2 = wave_red(a2); a3 = wave_red(a3);
  int wid = threadIdx.x >> 6;
  if ((threadIdx.x & 63) == 0) {
    blk[wid][0] = a0; blk[wid][1] = a1; blk[wid][2] = a2; blk[wid][3] = a3;
  }
  __syncthreads();
  if (threadIdx.x < 4) {
    float s = blk[0][threadIdx.x] + blk[1][threadIdx.x] + blk[2][threadIdx.x] +
              blk[3][threadIdx.x];
    atomicAdd(&hsum_new[threadIdx.x], (double)s);
  }
}

__global__ void node_post_final(const float* __restrict__ P, const float* __restrict__ deg,
                                const double* __restrict__ hsum, const float* __restrict__ beta_p,
                                const double* __restrict__ two_m, float* __restrict__ out_s,
                                double* __restrict__ comm_raw, int N) {
  __shared__ float blk[4][4];
  int n = blockIdx.x * blockDim.x + threadIdx.x;
  float scale = -beta_p[0] / (float)two_m[0];
  float e0 = expf(scale * (float)hsum[0]);
  float e1 = expf(scale * (float)hsum[1]);
  float e2 = expf(scale * (float)hsum[2]);
  float e3 = expf(scale * (float)hsum[3]);
  float a0 = 0.f, a1 = 0.f, a2 = 0.f, a3 = 0.f;
  if (n < N) {
    float4 Pv = *reinterpret_cast<const float4*>(&P[(size_t)n * QD]);
    float m0 = e0 * Pv.x, m1 = e1 * Pv.y, m2 = e2 * Pv.z, m3 = e3 * Pv.w;
    float inv = 1.f / (m0 + m1 + m2 + m3);
    float4 s = make_float4(m0 * inv, m1 * inv, m2 * inv, m3 * inv);
    *reinterpret_cast<float4*>(&out_s[(size_t)n * QD]) = s;
    float d = deg[n];
    a0 = d * s.x; a1 = d * s.y; a2 = d * s.z; a3 = d * s.w;
  }
  a0 = wave_red(a0); a1 = wave_red(a1); a2 = wave_red(a2); a3 = wave_red(a3);
  int wid = threadIdx.x >> 6;
  if ((threadIdx.x & 63) == 0) {
    blk[wid][0] = a0; blk[wid][1] = a1; blk[wid][2] = a2; blk[wid][3] = a3;
  }
  __syncthreads();
  if (threadIdx.x < 4) {
    float s = blk[0][threadIdx.x] + blk[1][threadIdx.x] + blk[2][threadIdx.x] +
              blk[3][threadIdx.x];
    atomicAdd(&comm_raw[threadIdx.x], (double)s);
  }
}

// ---- cavity update, product form on G=psi*em (fp16x4), 2 pairs/thread --
__global__ void edge_fuse(const int* __restrict__ ei, const float* __restrict__ em_buf,
                          const float* __restrict__ P, uint2* __restrict__ Gu,
                          const double* __restrict__ hsum, const float* __restrict__ beta_p,
                          const double* __restrict__ two_m, int E, int Eh) {
  int G = gridDim.x * blockDim.x;
  int t0 = blockIdx.x * blockDim.x + threadIdx.x;
  int t1 = t0 + G;
  float scale = -beta_p[0] / (float)two_m[0];
  float e0 = expf(scale * (float)hsum[0]);
  float e1 = expf(scale * (float)hsum[1]);
  float e2 = expf(scale * (float)hsum[2]);
  float e3 = expf(scale * (float)hsum[3]);
  int s1a = 0, d1a = 0, s1b = 0, d1b = 0;
  float ema = 0.f, emb = 0.f;
  if (t0 < Eh) { s1a = ei[t0]; d1a = ei[E + t0]; ema = em_buf[t0]; }
  if (t1 < Eh) { s1b = ei[t1]; d1b = ei[E + t1]; emb = em_buf[t1]; }
  uint2 G1a, G2a, G1b, G2b;
  float4 Psa, Pda, Psb, Pdb;
  if (t0 < Eh) {
    G1a = Gu[t0];
    G2a = Gu[(size_t)t0 + Eh];
    Psa = *reinterpret_cast<const float4*>(&P[(size_t)s1a * QD]);
    Pda = *reinterpret_cast<const float4*>(&P[(size_t)d1a * QD]);
  }
  if (t1 < Eh) {
    G1b = Gu[t1];
    G2b = Gu[(size_t)t1 + Eh];
    Psb = *reinterpret_cast<const float4*>(&P[(size_t)s1b * QD]);
    Pdb = *reinterpret_cast<const float4*>(&P[(size_t)d1b * QD]);
  }
#define CAV(Graw, Pn, em, dst_idx)                                       \
  {                                                                      \
    float g[4];                                                          \
    g_unpack(Graw, g);                                                   \
    float F0 = 1.f + g[0], F1 = 1.f + g[1], F2 = 1.f + g[2],             \
          F3 = 1.f + g[3];                                               \
    float a01 = F0 * F1, a23 = F2 * F3;                                  \
    float x0 = F1 * a23, x1 = F0 * a23, x2 = a01 * F3, x3 = a01 * F2;    \
    float n0 = e0 * (Pn).x * x0, n1 = e1 * (Pn).y * x1;                  \
    float n2 = e2 * (Pn).z * x2, n3 = e3 * (Pn).w * x3;                  \
    float tt = (em) / (n0 + n1 + n2 + n3);                               \
    Gu[dst_idx] = g_pack(n0 * tt, n1 * tt, n2 * tt, n3 * tt);            \
  }
  if (t0 < Eh) {
    CAV(G2a, Psa, ema, (size_t)t0);           // fwd edge uses rev's F (G2)
    CAV(G1a, Pda, ema, (size_t)t0 + Eh);      // rev edge uses fwd's F (G1)
  }
  if (t1 < Eh) {
    CAV(G2b, Psb, emb, (size_t)t1);
    CAV(G1b, Pdb, emb, (size_t)t1 + Eh);
  }
#undef CAV
}

__global__ void edge_final(const int* __restrict__ ei, const float* __restrict__ w,
                           const float* __restrict__ out_s,
                           double* __restrict__ link_raw, int E, int Eh) {
  __shared__ float blk[4];
  int G = gridDim.x * blockDim.x;
  float c = 0.f;
  for (int t = blockIdx.x * blockDim.x + threadIdx.x; t < Eh; t += G) {
    int s1 = ei[t];
    int d1 = ei[E + t];
    float4 a = *reinterpret_cast<const float4*>(&out_s[(size_t)s1 * QD]);
    float4 b = *reinterpret_cast<const float4*>(&out_s[(size_t)d1 * QD]);
    float dot = a.x * b.x + a.y * b.y + a.z * b.z + a.w * b.w;
    c += 2.f * w[t] * dot;
  }
  c = wave_red(c);
  int wid = threadIdx.x >> 6;
  if ((threadIdx.x & 63) == 0) blk[wid] = c;
  __syncthreads();
  if (threadIdx.x == 0)
    atomicAdd(link_raw, (double)(blk[0] + blk[1] + blk[2] + blk[3]));
}

__global__ void finalize(const double* __restrict__ scal, float* __restrict__ out_q) {
  double tm = scal[0];
  double link = scal[1] / tm;
  double acc = 0.0;
#pragma unroll
  for (int k = 0; k < QD; ++k) {
    double c = scal[2 + k] / tm;
    acc += c * c;
  }
  out_q[0] = (float)(link - acc);
}

extern "C" void kernel_launch(void* const* d_in, const int* in_sizes, int n_in,
                              void* d_out, int out_size, void* d_ws, size_t ws_size,
                              hipStream_t stream) {
  const int* ei = (const int*)d_in[0];         // [2,E] int32
  const float* w = (const float*)d_in[1];      // [E]
  const float* msg = (const float*)d_in[2];    // [E,4]
  const float* beta_p = (const float*)d_in[3]; // scalar

  const int E = in_sizes[1];
  const int Eh = E / 2;
  const int N = (out_size - 1) / QD;

  // ws: scal [0]=two_m [1]=link [2..5]=comm [6+4i..]=hsum (i=0..10)
  char* p = (char*)d_ws;
  double* scal = (double*)p;
  size_t off = 512;
  int* cnt = (int*)(p + off); off += (size_t)N * 4;
  int* rowStart = (int*)(p + off); off += (size_t)(N + 1) * 4;
  off = (off + 127) & ~(size_t)127;
  int* bsum = (int*)(p + off); off += 1024;
  int* inc = (int*)(p + off); off += (size_t)E * 4;
  float* deg = (float*)(p + off); off += (size_t)N * 4;
  off = (off + 15) & ~(size_t)15;
  float* P = (float*)(p + off); off += (size_t)N * QD * 4;
  float* em = (float*)(p + off); off += (size_t)Eh * 4;
  off = (off + 15) & ~(size_t)15;
  uint2* Gu = (uint2*)(p + off); off += (size_t)E * 8;  // 4xfp16 per edge
  int* rank = (int*)Gu;  // alias: rank (E*4B) dead before Gu written
  int* nodeOf = (int*)(p + off); off += (size_t)E * 4;
  (void)ws_size;

  double* hs = scal + 6;
  const int gE = (Eh + NBLK - 1) / NBLK;
  const int gE2 = (Eh / 2 + NBLK - 1) / NBLK + 1;
  const int gN = (N + NBLK - 1) / NBLK;
  const int gH = (E + NBLK * 8 - 1) / (NBLK * 8);
  const int gSc = (E + NBLK * 4 - 1) / (NBLK * 4);
  const int gWp = (E + 2047) / 2048;   // gather_seg<4,PROD,8>
  const int gWd = (E + 1023) / 1024;   // gather_seg<1,SUM,4>
  const int gF = (4 * N + NBLK - 1) / NBLK;
  const int NBscan = (N + 1023) / 1024;

  hipMemsetAsync(scal, 0, 512, stream);
  hipMemsetAsync(cnt, 0, (size_t)N * 4, stream);
  hipMemsetAsync(deg, 0, (size_t)N * 4, stream);

  hist_rank<<<gH, NBLK, 0, stream>>>(ei, cnt, rank, E);
  scanA<<<NBscan, 256, 0, stream>>>(cnt, rowStart, bsum, N);
  scanB<<<1, 256, 0, stream>>>(bsum, NBscan);
  scanC<<<(N + NBLK) / NBLK, NBLK, 0, stream>>>(rowStart, bsum, N, E);
  scatter_inc<<<gSc, NBLK, 0, stream>>>(ei, rowStart, rank, inc, E);
  build_nodeOf<<<gN, NBLK, 0, stream>>>(rowStart, nodeOf, N);

  setup_pairs<<<gE, NBLK, 0, stream>>>(w, msg, beta_p, Gu, em, scal, Eh);
  gather_seg<1, false, 4, false><<<gWd, NBLK, 0, stream>>>(inc, nodeOf, w, deg, E);

  float* out_s = (float*)d_out;
  for (int i = 1; i <= 11; ++i) {
    fillP<<<gF, NBLK, 0, stream>>>(P, 4 * N);
    gather_seg<4, true, 8, true><<<gWp, NBLK, 0, stream>>>(inc, nodeOf, Gu, P, E);
    if (i <= 10) {
      node_post<<<gN, NBLK, 0, stream>>>(P, deg, hs + 4 * (i - 1), hs + 4 * i,
                                         beta_p, scal, N);
      edge_fuse<<<gE2, NBLK, 0, stream>>>(ei, em, P, Gu, hs + 4 * i, beta_p,
                                          scal, E, Eh);
    }
  }
  node_post_final<<<gN, NBLK, 0, stream>>>(P, deg, hs + 40, beta_p, scal,
                                           out_s, scal + 2, N);
  edge_final<<<512, NBLK, 0, stream>>>(ei, w, out_s, scal + 1, E, Eh);
  finalize<<<1, 1, 0, stream>>>(scal, out_s + (size_t)N * QD);
}